// Round 13
// baseline (460.950 us; speedup 1.0000x reference)
//
#include <hip/hip_runtime.h>

#define D_DIM 128
#define EDGE_DIM 32
#define BN_EPS 1e-5f
#define CHUNK 128

typedef __attribute__((ext_vector_type(8))) _Float16 f16x8;
typedef __attribute__((ext_vector_type(2))) _Float16 half2v;
typedef __attribute__((ext_vector_type(4))) float f32x4;
typedef unsigned short ushort_t;

__device__ __forceinline__ unsigned short f2h(float f) {
    union { _Float16 h; unsigned short u; } c;
    c.h = (_Float16)f;
    return c.u;
}
__device__ __forceinline__ unsigned pk2h(float lo, float hi) {
    return (unsigned)f2h(lo) | ((unsigned)f2h(hi) << 16);
}
__device__ __forceinline__ half2v asH2(unsigned u) {
    union { unsigned u; half2v h; } c;
    c.u = u;
    return c.h;
}

// ---------------------------------------------------------------------------
// CSR build: histogram -> multi-block scan -> scatter(+fp16 convert)
// ---------------------------------------------------------------------------
__global__ __launch_bounds__(256) void hist_kernel(
    const int* __restrict__ dst, int* __restrict__ cnt, int E)
{
    for (int e = blockIdx.x * 256 + threadIdx.x; e < E; e += gridDim.x * 256)
        atomicAdd(&cnt[dst[e]], 1);
}

__global__ __launch_bounds__(256) void scan_local_kernel(
    const int* __restrict__ cnt, int* __restrict__ off,
    int* __restrict__ blksum, int n)
{
    __shared__ int part[256];
    const int t = threadIdx.x;
    const int base = blockIdx.x * 2048 + t * 8;
    int v[8];
    int s = 0;
#pragma unroll
    for (int j = 0; j < 8; ++j) {
        const int idx = base + j;
        const int c = (idx < n) ? cnt[idx] : 0;
        v[j] = s;
        s += c;
    }
    part[t] = s;
    __syncthreads();
    for (int d = 1; d < 256; d <<= 1) {
        const int val = (t >= d) ? part[t - d] : 0;
        __syncthreads();
        part[t] += val;
        __syncthreads();
    }
    const int texcl = (t > 0) ? part[t - 1] : 0;
#pragma unroll
    for (int j = 0; j < 8; ++j) {
        const int idx = base + j;
        if (idx < n) off[idx] = texcl + v[j];
    }
    if (t == 255) blksum[blockIdx.x] = part[255];
}

__global__ __launch_bounds__(64) void scan_tops_kernel(
    int* __restrict__ blksum, int* __restrict__ off, int n, int B)
{
    if (threadIdx.x == 0) {
        int run = 0;
        for (int b = 0; b < B; ++b) {
            const int v = blksum[b];
            blksum[b] = run;
            run += v;
        }
        off[n] = run;
    }
}

__global__ __launch_bounds__(256) void scan_add_kernel(
    int* __restrict__ off, int* __restrict__ cur,
    const int* __restrict__ blksum, int n)
{
    const int base = blockIdx.x * 2048;
    const int add = blksum[blockIdx.x];
    for (int j = threadIdx.x; j < 2048; j += 256) {
        const int i = base + j;
        if (i < n) {
            const int v = off[i] + add;
            off[i] = v;
            cur[i] = v;
        }
    }
}

// scatter + inline edge_attr fp16 conversion into CSR order (+dst array)
__global__ __launch_bounds__(256) void scatter_conv_kernel(
    const int* __restrict__ src, const int* __restrict__ dst,
    const float* __restrict__ ea,
    int* __restrict__ cur, int* __restrict__ srcs, int* __restrict__ dsts,
    uint4* __restrict__ ea16q, int E)
{
    for (int e = blockIdx.x * 256 + threadIdx.x; e < E; e += gridDim.x * 256) {
        const int d = dst[e];
        const int p = atomicAdd(&cur[d], 1);
        srcs[p] = src[e];
        dsts[p] = d;
        const float* __restrict__ er = ea + (size_t)e * EDGE_DIM;
#pragma unroll
        for (int q = 0; q < 4; ++q) {
            const float4 a = *(const float4*)(er + q * 8);
            const float4 b = *(const float4*)(er + q * 8 + 4);
            uint4 o;
            o.x = pk2h(a.x, a.y); o.y = pk2h(a.z, a.w);
            o.z = pk2h(b.x, b.y); o.w = pk2h(b.z, b.w);
            ea16q[(size_t)p * 4 + q] = o;
        }
    }
}

// ---------------------------------------------------------------------------
// Per-layer weight prep:
//   wflin : W_lin MFMA-B-fragment layout. slot s=cb*64+lane holds 8 halfs
//           W[(lane>>4)*8+j][cb*16+(lane&15)]   (2048 dwords)
//   wf1d/wf2d : W1/W2 fragment-linear, dword i: col=i>>6, kp=i&63,
//           pack(W[2kp][col], W[2kp+1][col])    (8192 dwords each)
// ---------------------------------------------------------------------------
__global__ __launch_bounds__(256) void wbuild_kernel(
    const float* __restrict__ Wl, const float* __restrict__ W1f,
    const float* __restrict__ W2f,
    unsigned* __restrict__ wflin, unsigned* __restrict__ wf1d,
    unsigned* __restrict__ wf2d)
{
    const int idx = blockIdx.x * 256 + threadIdx.x;
    if (idx < 2048) {
        const int slot = idx >> 2, q = idx & 3;
        const int cb = slot >> 6, lane = slot & 63;
        const int col = cb * 16 + (lane & 15);
        const int k0 = (lane >> 4) * 8 + 2 * q;
        wflin[idx] = pk2h(Wl[k0 * D_DIM + col], Wl[(k0 + 1) * D_DIM + col]);
    } else if (idx < 10240) {
        const int i = idx - 2048;
        const int col = i >> 6, kp = i & 63;
        wf1d[i] = pk2h(W1f[(2 * kp) * D_DIM + col], W1f[(2 * kp + 1) * D_DIM + col]);
    } else if (idx < 18432) {
        const int i = idx - 10240;
        const int col = i >> 6, kp = i & 63;
        wf2d[i] = pk2h(W2f[(2 * kp) * D_DIM + col], W2f[(2 * kp + 1) * D_DIM + col]);
    }
}

// ---------------------------------------------------------------------------
// xprep0: fp32 x -> fp16 x16 AND fp32 agg init (GIN self-term, layer 0)
// ---------------------------------------------------------------------------
__global__ __launch_bounds__(256) void xprep0_kernel(
    const float* __restrict__ h, uint2* __restrict__ x16q,
    float* __restrict__ aggf, int M)
{
    const int total = M * 32;
    for (int i = blockIdx.x * 256 + threadIdx.x; i < total; i += gridDim.x * 256) {
        const float4 v = ((const float4*)h)[i];
        uint2 o; o.x = pk2h(v.x, v.y); o.y = pk2h(v.z, v.w);
        x16q[i] = o;
        ((float4*)aggf)[i] = v;
    }
}

// ---------------------------------------------------------------------------
// apply: x = relu(h16*sc+sh). OUTF32=0: emit fp16 x16 + fp32 agg init.
//        OUTF32=1: emit fp32 out (final).
// ---------------------------------------------------------------------------
template<int OUTF32>
__global__ __launch_bounds__(256) void apply_kernel(
    const ushort_t* __restrict__ h16, const float* __restrict__ scsh,
    uint2* __restrict__ x16q, float* __restrict__ aggf,
    float* __restrict__ outp, int M)
{
    __shared__ float sc[128], sh[128];
    if (threadIdx.x < 128) {
        sc[threadIdx.x] = scsh[threadIdx.x];
        sh[threadIdx.x] = scsh[128 + threadIdx.x];
    }
    __syncthreads();
    const int total = M * 32;
    for (int i = blockIdx.x * 256 + threadIdx.x; i < total; i += gridDim.x * 256) {
        const uint2 hv = *(const uint2*)(h16 + (size_t)i * 4);
        const half2v a = asH2(hv.x), b = asH2(hv.y);
        const int c = (i & 31) * 4;
        const float v0 = fmaxf(fmaf((float)a.x, sc[c + 0], sh[c + 0]), 0.f);
        const float v1 = fmaxf(fmaf((float)a.y, sc[c + 1], sh[c + 1]), 0.f);
        const float v2 = fmaxf(fmaf((float)b.x, sc[c + 2], sh[c + 2]), 0.f);
        const float v3 = fmaxf(fmaf((float)b.y, sc[c + 3], sh[c + 3]), 0.f);
        if (OUTF32) {
            f32x4 o = {v0, v1, v2, v3};
            *(f32x4*)(outp + (size_t)i * 4) = o;
        } else {
            uint2 o; o.x = pk2h(v0, v1); o.y = pk2h(v2, v3);
            x16q[i] = o;
            f32x4 g = {v0, v1, v2, v3};
            *(f32x4*)(aggf + (size_t)i * 4) = g;
        }
    }
}

// ---------------------------------------------------------------------------
// Fused edge pass (per 128-edge chunk):
//   phase 1: e = ea@W_lin + b_lin via MFMA -> eT[edge][col] fp16 in LDS
//   phase 2: per-wave segmented reduce over 32 CSR positions, batch-4 ILP,
//            msg = relu(x16[src] + e); runs flushed to fp32 agg via atomics.
// agg pre-initialized to x (GIN self-term).
// ---------------------------------------------------------------------------
__global__ __launch_bounds__(256) void fused_edge_kernel(
    const unsigned* __restrict__ x16d,
    const int*      __restrict__ srcs,
    const int*      __restrict__ dsts,
    const ushort_t* __restrict__ ea16,    // (Epad) x 32 halfs, CSR order
    const ushort_t* __restrict__ wflin,   // B-fragment layout, 4096 halfs
    const float*    __restrict__ bl,
    float*          __restrict__ agg,
    int E)
{
    __shared__ ushort_t eT[CHUNK * 132];
    const int tid  = threadIdx.x;
    const int lane = tid & 63;
    const int w    = tid >> 6;
    const int fr   = lane & 15;
    const int fg   = lane >> 4;

    // ---- phase 1: MFMA e-tile ----
    f16x8 bfr[8];
#pragma unroll
    for (int cb = 0; cb < 8; ++cb)
        bfr[cb] = *(const f16x8*)(wflin + (cb * 64 + lane) * 8);
    float blv[8];
#pragma unroll
    for (int cb = 0; cb < 8; ++cb) blv[cb] = bl[cb * 16 + fr];

    const size_t chunk0 = (size_t)blockIdx.x * CHUNK;
#pragma unroll
    for (int rr = 0; rr < 2; ++rr) {
        const int rb = w * 2 + rr;
        const f16x8 af = *(const f16x8*)(ea16 + (chunk0 + rb * 16 + fr) * 32 + fg * 8);
        f32x4 acc[8];
#pragma unroll
        for (int cb = 0; cb < 8; ++cb) {
            const f32x4 z = {0.f, 0.f, 0.f, 0.f};
            acc[cb] = __builtin_amdgcn_mfma_f32_16x16x32_f16(af, bfr[cb], z, 0, 0, 0);
        }
#pragma unroll
        for (int cb = 0; cb < 8; ++cb) {
            const int col = cb * 16 + fr;
#pragma unroll
            for (int j = 0; j < 4; ++j) {
                const int er = rb * 16 + fg * 4 + j;
                eT[er * 132 + col] = f2h(acc[cb][j] + blv[cb]);
            }
        }
    }
    __syncthreads();

    // ---- phase 2: segmented reduce, batch-4 ----
    const int base = (int)chunk0 + w * 32;
    int nE = E - base;
    if (nE <= 0) return;
    if (nE > 32) nE = 32;
    const int pend = base + nE;

    float a0 = 0.f, a1 = 0.f;
    int p = base;

    auto flush = [&](int d) {
        unsafeAtomicAdd(&agg[(size_t)d * D_DIM + 2 * lane],     a0);
        unsafeAtomicAdd(&agg[(size_t)d * D_DIM + 2 * lane + 1], a1);
        a0 = 0.f; a1 = 0.f;
    };

#pragma unroll 1
    for (; p + 3 < pend; p += 4) {
        const int s0 = __builtin_amdgcn_readfirstlane(srcs[p]);
        const int s1 = __builtin_amdgcn_readfirstlane(srcs[p + 1]);
        const int s2 = __builtin_amdgcn_readfirstlane(srcs[p + 2]);
        const int s3 = __builtin_amdgcn_readfirstlane(srcs[p + 3]);
        const unsigned x0 = x16d[(size_t)s0 * 64 + lane];
        const unsigned x1 = x16d[(size_t)s1 * 64 + lane];
        const unsigned x2 = x16d[(size_t)s2 * 64 + lane];
        const unsigned x3 = x16d[(size_t)s3 * 64 + lane];
        const int ei = p - (int)chunk0;
        const unsigned e0 = *(const unsigned*)&eT[(ei + 0) * 132 + 2 * lane];
        const unsigned e1 = *(const unsigned*)&eT[(ei + 1) * 132 + 2 * lane];
        const unsigned e2 = *(const unsigned*)&eT[(ei + 2) * 132 + 2 * lane];
        const unsigned e3 = *(const unsigned*)&eT[(ei + 3) * 132 + 2 * lane];
        const int d0 = __builtin_amdgcn_readfirstlane(dsts[p]);
        const int d1 = __builtin_amdgcn_readfirstlane(dsts[p + 1]);
        const int d2 = __builtin_amdgcn_readfirstlane(dsts[p + 2]);
        const int d3 = __builtin_amdgcn_readfirstlane(dsts[p + 3]);
        const int d4 = (p + 4 < pend) ? __builtin_amdgcn_readfirstlane(dsts[p + 4]) : -1;

        { const half2v xh = asH2(x0), eh = asH2(e0);
          a0 += fmaxf((float)xh.x + (float)eh.x, 0.f);
          a1 += fmaxf((float)xh.y + (float)eh.y, 0.f);
          if (d0 != d1) flush(d0); }
        { const half2v xh = asH2(x1), eh = asH2(e1);
          a0 += fmaxf((float)xh.x + (float)eh.x, 0.f);
          a1 += fmaxf((float)xh.y + (float)eh.y, 0.f);
          if (d1 != d2) flush(d1); }
        { const half2v xh = asH2(x2), eh = asH2(e2);
          a0 += fmaxf((float)xh.x + (float)eh.x, 0.f);
          a1 += fmaxf((float)xh.y + (float)eh.y, 0.f);
          if (d2 != d3) flush(d2); }
        { const half2v xh = asH2(x3), eh = asH2(e3);
          a0 += fmaxf((float)xh.x + (float)eh.x, 0.f);
          a1 += fmaxf((float)xh.y + (float)eh.y, 0.f);
          if (d3 != d4) flush(d3); }
    }
#pragma unroll 1
    for (; p < pend; ++p) {   // generic tail (unused when E%4==0)
        const int s = __builtin_amdgcn_readfirstlane(srcs[p]);
        const unsigned xd = x16d[(size_t)s * 64 + lane];
        const int ei = p - (int)chunk0;
        const unsigned ed = *(const unsigned*)&eT[ei * 132 + 2 * lane];
        const int d  = __builtin_amdgcn_readfirstlane(dsts[p]);
        const int dn = (p + 1 < pend) ? __builtin_amdgcn_readfirstlane(dsts[p + 1]) : -1;
        const half2v xh = asH2(xd), eh = asH2(ed);
        a0 += fmaxf((float)xh.x + (float)eh.x, 0.f);
        a1 += fmaxf((float)xh.y + (float)eh.y, 0.f);
        if (d != dn) flush(d);
    }
}

// ---------------------------------------------------------------------------
// Fused MLP: h16 = (relu(agg@W1+b1)) @ W2 + b2 (+BN sums). agg is fp32
// (x + scatter result). A in LDS (32 KB swizzled); B from global wfrag.
// ---------------------------------------------------------------------------
__global__ __launch_bounds__(256) void fused_mlp_kernel(
    const float* __restrict__ agg,
    const ushort_t* __restrict__ wf1,
    const float* __restrict__ b1,
    const ushort_t* __restrict__ wf2,
    const float* __restrict__ b2,
    ushort_t* __restrict__ h16,
    float* __restrict__ sums,
    int M)
{
    __shared__ char ATb[128 * 256];
    __shared__ float bsum[256];
    const int tid = threadIdx.x;
    const int m0  = blockIdx.x * 128;

    bsum[tid] = 0.f;

    // --- stage A: fp32 agg -> fp16, XOR-swizzled ---
#pragma unroll
    for (int i = 0; i < 16; ++i) {
        const int idx = i * 256 + tid;
        const int r = idx >> 5, c4 = idx & 31;
        const int row = m0 + r;
        f32x4 v = {0.f, 0.f, 0.f, 0.f};
        if (row < M) v = *(const f32x4*)(agg + (size_t)row * 128 + c4 * 4);
        uint2 pk; pk.x = pk2h(v[0], v[1]); pk.y = pk2h(v[2], v[3]);
        *(uint2*)(ATb + r * 256 + ((c4 * 8) ^ ((r & 7) << 4))) = pk;
    }
    __syncthreads();

    const int lane = tid & 63;
    const int w    = tid >> 6;
    const int fr   = lane & 15;
    const int fg   = lane >> 4;
    const int ar0  = w * 32 + fr;
    const int asz  = (ar0 & 7) << 4;

    f32x4 acc[2][8];
#pragma unroll
    for (int a = 0; a < 2; ++a)
#pragma unroll
        for (int b = 0; b < 8; ++b) acc[a][b] = (f32x4){0.f, 0.f, 0.f, 0.f};

#pragma unroll
    for (int ks = 0; ks < 4; ++ks) {
        const int kb = ks * 64 + fg * 16;
        const f16x8 a0 = *(const f16x8*)(ATb + ar0 * 256 + (kb ^ asz));
        const f16x8 a1 = *(const f16x8*)(ATb + (ar0 + 16) * 256 + (kb ^ asz));
        f16x8 bf[8];
#pragma unroll
        for (int cb = 0; cb < 8; ++cb)
            bf[cb] = *(const f16x8*)(wf1 + (cb * 16 + fr) * 128 + ks * 32 + fg * 8);
#pragma unroll
        for (int cb = 0; cb < 8; ++cb) {
            acc[0][cb] = __builtin_amdgcn_mfma_f32_16x16x32_f16(a0, bf[cb], acc[0][cb], 0, 0, 0);
            acc[1][cb] = __builtin_amdgcn_mfma_f32_16x16x32_f16(a1, bf[cb], acc[1][cb], 0, 0, 0);
        }
    }
    __syncthreads();

    {
        float b1v[8];
#pragma unroll
        for (int cb = 0; cb < 8; ++cb) b1v[cb] = b1[cb * 16 + fr];
#pragma unroll
        for (int rf = 0; rf < 2; ++rf) {
            const int rb = w * 32 + rf * 16 + fg * 4;
#pragma unroll
            for (int cb = 0; cb < 8; ++cb) {
                const int c = cb * 16 + fr;
#pragma unroll
                for (int j = 0; j < 4; ++j) {
                    const int r = rb + j;
                    const float v = fmaxf(acc[rf][cb][j] + b1v[cb], 0.f);
                    *(ushort_t*)(ATb + r * 256 + ((c * 2) ^ ((r & 7) << 4))) = f2h(v);
                }
            }
        }
    }
#pragma unroll
    for (int a = 0; a < 2; ++a)
#pragma unroll
        for (int b = 0; b < 8; ++b) acc[a][b] = (f32x4){0.f, 0.f, 0.f, 0.f};
    __syncthreads();

#pragma unroll
    for (int ks = 0; ks < 4; ++ks) {
        const int kb = ks * 64 + fg * 16;
        const f16x8 a0 = *(const f16x8*)(ATb + ar0 * 256 + (kb ^ asz));
        const f16x8 a1 = *(const f16x8*)(ATb + (ar0 + 16) * 256 + (kb ^ asz));
        f16x8 bf[8];
#pragma unroll
        for (int cb = 0; cb < 8; ++cb)
            bf[cb] = *(const f16x8*)(wf2 + (cb * 16 + fr) * 128 + ks * 32 + fg * 8);
#pragma unroll
        for (int cb = 0; cb < 8; ++cb) {
            acc[0][cb] = __builtin_amdgcn_mfma_f32_16x16x32_f16(a0, bf[cb], acc[0][cb], 0, 0, 0);
            acc[1][cb] = __builtin_amdgcn_mfma_f32_16x16x32_f16(a1, bf[cb], acc[1][cb], 0, 0, 0);
        }
    }

    float b2v[8];
#pragma unroll
    for (int cb = 0; cb < 8; ++cb) b2v[cb] = b2[cb * 16 + fr];
    float s[8], q[8];
#pragma unroll
    for (int cb = 0; cb < 8; ++cb) { s[cb] = 0.f; q[cb] = 0.f; }

#pragma unroll
    for (int rf = 0; rf < 2; ++rf) {
        const int r0 = m0 + w * 32 + rf * 16 + fg * 4;
#pragma unroll
        for (int cb = 0; cb < 8; ++cb) {
            const int col = cb * 16 + fr;
#pragma unroll
            for (int j = 0; j < 4; ++j) {
                const int row = r0 + j;
                if (row < M) {
                    const float v = acc[rf][cb][j] + b2v[cb];
                    h16[(size_t)row * 128 + col] = f2h(v);
                    s[cb] += v;
                    q[cb] += v * v;
                }
            }
        }
    }
#pragma unroll
    for (int cb = 0; cb < 8; ++cb) {
        float ss = s[cb]; ss += __shfl_down(ss, 32); ss += __shfl_down(ss, 16);
        float qq = q[cb]; qq += __shfl_down(qq, 32); qq += __shfl_down(qq, 16);
        if (lane < 16) {
            atomicAdd(&bsum[cb * 16 + lane], ss);
            atomicAdd(&bsum[128 + cb * 16 + lane], qq);
        }
    }
    __syncthreads();
    unsafeAtomicAdd(&sums[tid], bsum[tid]);
}

// ---------------------------------------------------------------------------
__global__ __launch_bounds__(128) void bn_finalize_kernel(
    const float* __restrict__ sums,
    const float* __restrict__ gamma, const float* __restrict__ beta,
    float* __restrict__ scsh, float invM)
{
    const int c = threadIdx.x;
    const float mu  = sums[c] * invM;
    const float var = sums[128 + c] * invM - mu * mu;
    const float sc  = gamma[c] * rsqrtf(var + BN_EPS);
    scsh[c]       = sc;
    scsh[128 + c] = beta[c] - mu * sc;
}

// ---------------------------------------------------------------------------
extern "C" void kernel_launch(void* const* d_in, const int* in_sizes, int n_in,
                              void* d_out, int out_size, void* d_ws, size_t ws_size,
                              hipStream_t stream)
{
    const float* x_in  = (const float*)d_in[0];
    const int*   ei    = (const int*)  d_in[1];
    const float* ea    = (const float*)d_in[2];
    const float* W_lin = (const float*)d_in[3];
    const float* b_lin = (const float*)d_in[4];
    const float* W1    = (const float*)d_in[5];
    const float* b1    = (const float*)d_in[6];
    const float* W2    = (const float*)d_in[7];
    const float* b2    = (const float*)d_in[8];
    const float* gamma = (const float*)d_in[9];
    const float* beta  = (const float*)d_in[10];

    const int N = in_sizes[0] / D_DIM;              // 50000
    const int E = in_sizes[2] / EDGE_DIM;           // 600000
    const int L = in_sizes[3] / (EDGE_DIM * D_DIM); // 3
    const int Epad = (E + CHUNK - 1) & ~(CHUNK - 1);

    const int* src = ei;
    const int* dst = ei + E;

    float* out = (float*)d_out;

    char* wp = (char*)d_ws;
    auto take = [&wp](size_t bytes) {
        char* r = wp;
        wp += (bytes + 15) & ~(size_t)15;
        return r;
    };
    float*     agg     = (float*)    take((size_t)N * D_DIM * 4);
    ushort_t*  h16     = (ushort_t*) take((size_t)N * D_DIM * 2);
    unsigned*  x16d    = (unsigned*) take((size_t)N * D_DIM * 2);
    float*     sums    = (float*)    take(256 * 4);
    float*     scsh    = (float*)    take(256 * 4);
    unsigned*  wflin   = (unsigned*) take(2048 * 4);
    unsigned*  wf1d    = (unsigned*) take(8192 * 4);
    unsigned*  wf2d    = (unsigned*) take(8192 * 4);
    int*       cnt     = (int*)      take((size_t)N * 4);
    int*       row_off = (int*)      take((size_t)(N + 1) * 4);
    int*       cur     = (int*)      take((size_t)N * 4);
    int*       blksum  = (int*)      take(256 * 4);
    int*       srcs    = (int*)      take((size_t)E * 4);
    int*       dsts    = (int*)      take((size_t)E * 4);
    uint4*     ea16q   = (uint4*)    take((size_t)Epad * 64);

    const int gemmBlocks = (N + 127) / 128;
    const int scanBlocks = (N + 2047) / 2048;
    const int edgeBlocks = Epad / CHUNK;

    hipMemsetAsync(cnt, 0, (size_t)N * sizeof(int), stream);
    hist_kernel<<<1024, 256, 0, stream>>>(dst, cnt, E);
    scan_local_kernel<<<scanBlocks, 256, 0, stream>>>(cnt, row_off, blksum, N);
    scan_tops_kernel<<<1, 64, 0, stream>>>(blksum, row_off, N, scanBlocks);
    scan_add_kernel<<<scanBlocks, 256, 0, stream>>>(row_off, cur, blksum, N);
    scatter_conv_kernel<<<1024, 256, 0, stream>>>(src, dst, ea, cur, srcs, dsts, ea16q, E);

    for (int l = 0; l < L; ++l) {
        hipMemsetAsync(sums, 0, 256 * sizeof(float), stream);

        const float* Wl_l = W_lin + (size_t)l * EDGE_DIM * D_DIM;
        const float* bl_l = b_lin + (size_t)l * D_DIM;
        const float* W1_l = W1 + (size_t)l * D_DIM * D_DIM;
        const float* b1_l = b1 + (size_t)l * D_DIM;
        const float* W2_l = W2 + (size_t)l * D_DIM * D_DIM;
        const float* b2_l = b2 + (size_t)l * D_DIM;

        if (l == 0)
            xprep0_kernel<<<1024, 256, 0, stream>>>(x_in, (uint2*)x16d, agg, N);
        else
            apply_kernel<0><<<1024, 256, 0, stream>>>(h16, scsh, (uint2*)x16d, agg, nullptr, N);

        wbuild_kernel<<<72, 256, 0, stream>>>(Wl_l, W1_l, W2_l, wflin, wf1d, wf2d);

        fused_edge_kernel<<<edgeBlocks, 256, 0, stream>>>(
            x16d, srcs, dsts, (const ushort_t*)ea16q,
            (const ushort_t*)wflin, bl_l, agg, E);

        fused_mlp_kernel<<<gemmBlocks, 256, 0, stream>>>(
            agg, (const ushort_t*)wf1d, b1_l,
            (const ushort_t*)wf2d, b2_l, h16, sums, N);

        bn_finalize_kernel<<<1, 128, 0, stream>>>(
            sums, gamma + (size_t)l * D_DIM, beta + (size_t)l * D_DIM,
            scsh, 1.f / (float)N);
    }

    apply_kernel<1><<<1024, 256, 0, stream>>>(h16, scsh, nullptr, nullptr, out, N);
}

// Round 14
// 447.035 us; speedup vs baseline: 1.0311x; 1.0311x over previous
//
#include <hip/hip_runtime.h>

#define D_DIM 128
#define EDGE_DIM 32
#define BN_EPS 1e-5f
#define CHUNK 128
#define ECAP 192

typedef __attribute__((ext_vector_type(8))) _Float16 f16x8;
typedef __attribute__((ext_vector_type(2))) _Float16 half2v;
typedef __attribute__((ext_vector_type(4))) float f32x4;
typedef unsigned short ushort_t;

__device__ __forceinline__ unsigned short f2h(float f) {
    union { _Float16 h; unsigned short u; } c;
    c.h = (_Float16)f;
    return c.u;
}
__device__ __forceinline__ unsigned pk2h(float lo, float hi) {
    return (unsigned)f2h(lo) | ((unsigned)f2h(hi) << 16);
}
__device__ __forceinline__ half2v asH2(unsigned u) {
    union { unsigned u; half2v h; } c;
    c.u = u;
    return c.h;
}

// ---------------------------------------------------------------------------
// CSR build: histogram -> multi-block scan -> scatter(+fp16 convert)
// ---------------------------------------------------------------------------
__global__ __launch_bounds__(256) void hist_kernel(
    const int* __restrict__ dst, int* __restrict__ cnt, int E)
{
    for (int e = blockIdx.x * 256 + threadIdx.x; e < E; e += gridDim.x * 256)
        atomicAdd(&cnt[dst[e]], 1);
}

__global__ __launch_bounds__(256) void scan_local_kernel(
    const int* __restrict__ cnt, int* __restrict__ off,
    int* __restrict__ blksum, int n)
{
    __shared__ int part[256];
    const int t = threadIdx.x;
    const int base = blockIdx.x * 2048 + t * 8;
    int v[8];
    int s = 0;
#pragma unroll
    for (int j = 0; j < 8; ++j) {
        const int idx = base + j;
        const int c = (idx < n) ? cnt[idx] : 0;
        v[j] = s;
        s += c;
    }
    part[t] = s;
    __syncthreads();
    for (int d = 1; d < 256; d <<= 1) {
        const int val = (t >= d) ? part[t - d] : 0;
        __syncthreads();
        part[t] += val;
        __syncthreads();
    }
    const int texcl = (t > 0) ? part[t - 1] : 0;
#pragma unroll
    for (int j = 0; j < 8; ++j) {
        const int idx = base + j;
        if (idx < n) off[idx] = texcl + v[j];
    }
    if (t == 255) blksum[blockIdx.x] = part[255];
}

__global__ __launch_bounds__(64) void scan_tops_kernel(
    int* __restrict__ blksum, int* __restrict__ off, int n, int B)
{
    if (threadIdx.x == 0) {
        int run = 0;
        for (int b = 0; b < B; ++b) {
            const int v = blksum[b];
            blksum[b] = run;
            run += v;
        }
        off[n] = run;
    }
}

__global__ __launch_bounds__(256) void scan_add_kernel(
    int* __restrict__ off, int* __restrict__ cur,
    const int* __restrict__ blksum, int n)
{
    const int base = blockIdx.x * 2048;
    const int add = blksum[blockIdx.x];
    for (int j = threadIdx.x; j < 2048; j += 256) {
        const int i = base + j;
        if (i < n) {
            const int v = off[i] + add;
            off[i] = v;
            cur[i] = v;
        }
    }
}

// scatter + inline edge_attr fp16 conversion into CSR order
__global__ __launch_bounds__(256) void scatter_conv_kernel(
    const int* __restrict__ src, const int* __restrict__ dst,
    const float* __restrict__ ea,
    int* __restrict__ cur, int* __restrict__ srcs,
    uint4* __restrict__ ea16q, int E)
{
    for (int e = blockIdx.x * 256 + threadIdx.x; e < E; e += gridDim.x * 256) {
        const int p = atomicAdd(&cur[dst[e]], 1);
        srcs[p] = src[e];
        const float* __restrict__ er = ea + (size_t)e * EDGE_DIM;
#pragma unroll
        for (int q = 0; q < 4; ++q) {
            const float4 a = *(const float4*)(er + q * 8);
            const float4 b = *(const float4*)(er + q * 8 + 4);
            uint4 o;
            o.x = pk2h(a.x, a.y); o.y = pk2h(a.z, a.w);
            o.z = pk2h(b.x, b.y); o.w = pk2h(b.z, b.w);
            ea16q[(size_t)p * 4 + q] = o;
        }
    }
}

// ---------------------------------------------------------------------------
// chunk_first[c] = first node whose CSR row starts in edge-window c.
// chunk_first pre-filled with 0x7f7f7f7f; [nchunks] set to n here.
// ---------------------------------------------------------------------------
__global__ __launch_bounds__(256) void chunk_first_kernel(
    const int* __restrict__ row_off, int* __restrict__ chunk_first,
    int n, int nchunks)
{
    const int i = blockIdx.x * 256 + threadIdx.x;
    if (i == 0) chunk_first[nchunks] = n;
    if (i < n) {
        int c = row_off[i] >> 7;
        if (c > nchunks - 1) c = nchunks - 1;
        atomicMin(&chunk_first[c], i);
    }
}

// ---------------------------------------------------------------------------
// W_lin -> MFMA B-fragment layout: slot s=cb*64+lane holds 8 halfs
// W[(lane>>4)*8+j][cb*16+(lane&15)]   (2048 dwords)
// ---------------------------------------------------------------------------
__global__ __launch_bounds__(256) void wlin_build_kernel(
    const float* __restrict__ Wl, unsigned* __restrict__ wflin)
{
    const int idx = blockIdx.x * 256 + threadIdx.x;   // 0..2047
    const int slot = idx >> 2, q = idx & 3;
    const int cb = slot >> 6, lane = slot & 63;
    const int col = cb * 16 + (lane & 15);
    const int k0 = (lane >> 4) * 8 + 2 * q;
    wflin[idx] = pk2h(Wl[k0 * D_DIM + col], Wl[(k0 + 1) * D_DIM + col]);
}

// ---------------------------------------------------------------------------
// xprep0: fp32 x -> fp16 x16 (layer 0 only)
// ---------------------------------------------------------------------------
__global__ __launch_bounds__(256) void xprep0_kernel(
    const float* __restrict__ h, uint2* __restrict__ x16q, int M)
{
    const int total = M * 32;
    for (int i = blockIdx.x * 256 + threadIdx.x; i < total; i += gridDim.x * 256) {
        const float4 v = ((const float4*)h)[i];
        uint2 o; o.x = pk2h(v.x, v.y); o.y = pk2h(v.z, v.w);
        x16q[i] = o;
    }
}

// ---------------------------------------------------------------------------
// apply: x = relu(h16*sc + sh); emit fp16 x16 (OUTF32=0) or fp32 out (=1)
// ---------------------------------------------------------------------------
template<int OUTF32>
__global__ __launch_bounds__(256) void apply_kernel(
    const ushort_t* __restrict__ h16, const float* __restrict__ scsh,
    uint2* __restrict__ x16q, float* __restrict__ outp, int M)
{
    __shared__ float sc[128], sh[128];
    if (threadIdx.x < 128) {
        sc[threadIdx.x] = scsh[threadIdx.x];
        sh[threadIdx.x] = scsh[128 + threadIdx.x];
    }
    __syncthreads();
    const int total = M * 32;
    for (int i = blockIdx.x * 256 + threadIdx.x; i < total; i += gridDim.x * 256) {
        const uint2 hv = *(const uint2*)(h16 + (size_t)i * 4);
        const half2v a = asH2(hv.x), b = asH2(hv.y);
        const int c = (i & 31) * 4;
        const float v0 = fmaxf(fmaf((float)a.x, sc[c + 0], sh[c + 0]), 0.f);
        const float v1 = fmaxf(fmaf((float)a.y, sc[c + 1], sh[c + 1]), 0.f);
        const float v2 = fmaxf(fmaf((float)b.x, sc[c + 2], sh[c + 2]), 0.f);
        const float v3 = fmaxf(fmaf((float)b.y, sc[c + 3], sh[c + 3]), 0.f);
        if (OUTF32) {
            f32x4 o = {v0, v1, v2, v3};
            *(f32x4*)(outp + (size_t)i * 4) = o;
        } else {
            uint2 o; o.x = pk2h(v0, v1); o.y = pk2h(v2, v3);
            x16q[i] = o;
        }
    }
}

// ---------------------------------------------------------------------------
// Fused edge pass, node-aligned chunks:
//   phase 1: e = ea@W_lin + b_lin via MFMA -> eT[edge][col] fp16 in LDS
//   phase 2: waves split the chunk's nodes; per node batch-4 gather
//            x16[src] + e, plain-store agg16[n] = fp16(x[n] + sum(relu)).
// No atomics. Chunk edge count <= 127 + max_degree <= ECAP.
// ---------------------------------------------------------------------------
__global__ __launch_bounds__(256, 3) void fused_edge_kernel(
    const unsigned* __restrict__ x16d,
    const int*      __restrict__ srcs,
    const ushort_t* __restrict__ ea16,
    const ushort_t* __restrict__ wflin,
    const float*    __restrict__ bl,
    const int*      __restrict__ row_off,
    const int*      __restrict__ chunk_first,
    unsigned*       __restrict__ agg16d,
    int nNodes)
{
    __shared__ ushort_t eT[ECAP * 132];
    const int tid  = threadIdx.x;
    const int lane = tid & 63;
    const int w    = tid >> 6;
    const int fr   = lane & 15;
    const int fg   = lane >> 4;
    const int c    = blockIdx.x;

    int nfirst = chunk_first[c];
    int nlast  = chunk_first[c + 1];
    if (nfirst > nNodes) nfirst = nNodes;
    if (nlast  > nNodes) nlast  = nNodes;
    if (nfirst >= nlast) return;      // block-uniform; barrier never reached
    const int ebase = row_off[nfirst];
    const int ecnt  = row_off[nlast] - ebase;

    // ---- phase 1: MFMA e-tile ----
    f16x8 bfr[8];
#pragma unroll
    for (int cb = 0; cb < 8; ++cb)
        bfr[cb] = *(const f16x8*)(wflin + (cb * 64 + lane) * 8);
    float blv[8];
#pragma unroll
    for (int cb = 0; cb < 8; ++cb) blv[cb] = bl[cb * 16 + fr];

    const int rowblocks = (ecnt + 15) >> 4;   // <= ECAP/16 = 12
#pragma unroll
    for (int rr = 0; rr < 3; ++rr) {
        const int rb = w + rr * 4;
        if (rb < rowblocks) {
            const f16x8 af = *(const f16x8*)(ea16
                + ((size_t)(ebase + rb * 16 + fr)) * 32 + fg * 8);
            f32x4 acc[8];
#pragma unroll
            for (int cb = 0; cb < 8; ++cb) {
                const f32x4 z = {0.f, 0.f, 0.f, 0.f};
                acc[cb] = __builtin_amdgcn_mfma_f32_16x16x32_f16(af, bfr[cb], z, 0, 0, 0);
            }
#pragma unroll
            for (int cb = 0; cb < 8; ++cb) {
                const int col = cb * 16 + fr;
#pragma unroll
                for (int j = 0; j < 4; ++j) {
                    const int er = rb * 16 + fg * 4 + j;
                    eT[er * 132 + col] = f2h(acc[cb][j] + blv[cb]);
                }
            }
        }
    }
    __syncthreads();

    // ---- phase 2: node-parallel, batch-4 ILP, plain stores ----
    for (int n = nfirst + w; n < nlast; n += 4) {
        const int beg = __builtin_amdgcn_readfirstlane(row_off[n]);
        const int end = __builtin_amdgcn_readfirstlane(row_off[n + 1]);
        float a0 = 0.f, a1 = 0.f;
        int p = beg;
        const int head = (end - beg) & 3;
#pragma unroll 1
        for (int t = 0; t < head; ++t, ++p) {
            const int s = __builtin_amdgcn_readfirstlane(srcs[p]);
            const unsigned xd = x16d[(size_t)s * 64 + lane];
            const unsigned ed = *(const unsigned*)&eT[(p - ebase) * 132 + 2 * lane];
            const half2v xh = asH2(xd), eh = asH2(ed);
            a0 += fmaxf((float)xh.x + (float)eh.x, 0.f);
            a1 += fmaxf((float)xh.y + (float)eh.y, 0.f);
        }
#pragma unroll 1
        for (; p < end; p += 4) {
            const int s0 = __builtin_amdgcn_readfirstlane(srcs[p]);
            const int s1 = __builtin_amdgcn_readfirstlane(srcs[p + 1]);
            const int s2 = __builtin_amdgcn_readfirstlane(srcs[p + 2]);
            const int s3 = __builtin_amdgcn_readfirstlane(srcs[p + 3]);
            const unsigned x0 = x16d[(size_t)s0 * 64 + lane];
            const unsigned x1 = x16d[(size_t)s1 * 64 + lane];
            const unsigned x2 = x16d[(size_t)s2 * 64 + lane];
            const unsigned x3 = x16d[(size_t)s3 * 64 + lane];
            const int ei = p - ebase;
            const unsigned e0 = *(const unsigned*)&eT[(ei + 0) * 132 + 2 * lane];
            const unsigned e1 = *(const unsigned*)&eT[(ei + 1) * 132 + 2 * lane];
            const unsigned e2 = *(const unsigned*)&eT[(ei + 2) * 132 + 2 * lane];
            const unsigned e3 = *(const unsigned*)&eT[(ei + 3) * 132 + 2 * lane];
            { const half2v xh = asH2(x0), eh = asH2(e0);
              a0 += fmaxf((float)xh.x + (float)eh.x, 0.f);
              a1 += fmaxf((float)xh.y + (float)eh.y, 0.f); }
            { const half2v xh = asH2(x1), eh = asH2(e1);
              a0 += fmaxf((float)xh.x + (float)eh.x, 0.f);
              a1 += fmaxf((float)xh.y + (float)eh.y, 0.f); }
            { const half2v xh = asH2(x2), eh = asH2(e2);
              a0 += fmaxf((float)xh.x + (float)eh.x, 0.f);
              a1 += fmaxf((float)xh.y + (float)eh.y, 0.f); }
            { const half2v xh = asH2(x3), eh = asH2(e3);
              a0 += fmaxf((float)xh.x + (float)eh.x, 0.f);
              a1 += fmaxf((float)xh.y + (float)eh.y, 0.f); }
        }
        // GIN self-term folded: agg16 = fp16(x + sum)
        const half2v xh = asH2(x16d[(size_t)n * 64 + lane]);
        agg16d[(size_t)n * 64 + lane] =
            pk2h((float)xh.x + a0, (float)xh.y + a1);
    }
}

// ---------------------------------------------------------------------------
// Fused MLP: h16 = (relu(agg16@W1+b1)) @ W2 + b2 (+BN sums).
// A staged as pure fp16 copy; W1/W2 staged fp32->fp16 into LDS (R11 form).
// ---------------------------------------------------------------------------
__global__ __launch_bounds__(256) void fused_mlp_kernel(
    const unsigned* __restrict__ agg16d,
    const float* __restrict__ W1,
    const float* __restrict__ b1,
    const float* __restrict__ W2,
    const float* __restrict__ b2,
    ushort_t* __restrict__ h16,
    float* __restrict__ sums,
    int M)
{
    __shared__ char ATb[128 * 256];
    __shared__ char WTb[128 * 256];
    __shared__ float bsum[256];
    const int tid = threadIdx.x;
    const int m0  = blockIdx.x * 128;

    bsum[tid] = 0.f;

    // --- stage A: pure fp16 copy, XOR-swizzled ---
#pragma unroll
    for (int i = 0; i < 8; ++i) {
        const int idx = i * 256 + tid;
        const int r = idx >> 4, c16 = idx & 15;
        const int row = m0 + r;
        uint4 v = make_uint4(0u, 0u, 0u, 0u);
        if (row < M) v = *(const uint4*)(agg16d + (size_t)row * 64 + c16 * 4);
        *(uint4*)(ATb + r * 256 + ((c16 * 16) ^ ((r & 7) << 4))) = v;
    }
    // --- stage W1 ---
#pragma unroll
    for (int i = 0; i < 8; ++i) {
        const int c4 = (tid >> 6) + 4 * i;
        const int kp = tid & 63;
        const f32x4 wa = *(const f32x4*)(W1 + (size_t)(2 * kp) * 128 + c4 * 4);
        const f32x4 wb = *(const f32x4*)(W1 + (size_t)(2 * kp + 1) * 128 + c4 * 4);
#pragma unroll
        for (int j = 0; j < 4; ++j) {
            const int col = c4 * 4 + j;
            *(unsigned*)(WTb + col * 256 + ((kp * 4) ^ ((col & 7) << 4))) = pk2h(wa[j], wb[j]);
        }
    }
    __syncthreads();

    const int lane = tid & 63;
    const int w    = tid >> 6;
    const int fr   = lane & 15;
    const int fg   = lane >> 4;
    const int ar0  = w * 32 + fr;
    const int asz  = (ar0 & 7) << 4;

    f32x4 acc[2][8];
#pragma unroll
    for (int a = 0; a < 2; ++a)
#pragma unroll
        for (int b = 0; b < 8; ++b) acc[a][b] = (f32x4){0.f, 0.f, 0.f, 0.f};

#pragma unroll
    for (int ks = 0; ks < 4; ++ks) {
        const int kb = ks * 64 + fg * 16;
        const f16x8 a0 = *(const f16x8*)(ATb + ar0 * 256 + (kb ^ asz));
        const f16x8 a1 = *(const f16x8*)(ATb + (ar0 + 16) * 256 + (kb ^ asz));
#pragma unroll
        for (int cb = 0; cb < 8; ++cb) {
            const int col = cb * 16 + fr;
            const f16x8 b = *(const f16x8*)(WTb + col * 256 + (kb ^ ((col & 7) << 4)));
            acc[0][cb] = __builtin_amdgcn_mfma_f32_16x16x32_f16(a0, b, acc[0][cb], 0, 0, 0);
            acc[1][cb] = __builtin_amdgcn_mfma_f32_16x16x32_f16(a1, b, acc[1][cb], 0, 0, 0);
        }
    }
    __syncthreads();

    // --- write relu(h1) tile into ATb (fp16, same swizzled layout) ---
    {
        float b1v[8];
#pragma unroll
        for (int cb = 0; cb < 8; ++cb) b1v[cb] = b1[cb * 16 + fr];
#pragma unroll
        for (int rf = 0; rf < 2; ++rf) {
            const int rb = w * 32 + rf * 16 + fg * 4;
#pragma unroll
            for (int cb = 0; cb < 8; ++cb) {
                const int cc = cb * 16 + fr;
#pragma unroll
                for (int j = 0; j < 4; ++j) {
                    const int r = rb + j;
                    const float v = fmaxf(acc[rf][cb][j] + b1v[cb], 0.f);
                    *(ushort_t*)(ATb + r * 256 + ((cc * 2) ^ ((r & 7) << 4))) = f2h(v);
                }
            }
        }
    }
    // --- stage W2 ---
#pragma unroll
    for (int i = 0; i < 8; ++i) {
        const int c4 = (tid >> 6) + 4 * i;
        const int kp = tid & 63;
        const f32x4 wa = *(const f32x4*)(W2 + (size_t)(2 * kp) * 128 + c4 * 4);
        const f32x4 wb = *(const f32x4*)(W2 + (size_t)(2 * kp + 1) * 128 + c4 * 4);
#pragma unroll
        for (int j = 0; j < 4; ++j) {
            const int col = c4 * 4 + j;
            *(unsigned*)(WTb + col * 256 + ((kp * 4) ^ ((col & 7) << 4))) = pk2h(wa[j], wb[j]);
        }
    }
#pragma unroll
    for (int a = 0; a < 2; ++a)
#pragma unroll
        for (int b = 0; b < 8; ++b) acc[a][b] = (f32x4){0.f, 0.f, 0.f, 0.f};
    __syncthreads();

#pragma unroll
    for (int ks = 0; ks < 4; ++ks) {
        const int kb = ks * 64 + fg * 16;
        const f16x8 a0 = *(const f16x8*)(ATb + ar0 * 256 + (kb ^ asz));
        const f16x8 a1 = *(const f16x8*)(ATb + (ar0 + 16) * 256 + (kb ^ asz));
#pragma unroll
        for (int cb = 0; cb < 8; ++cb) {
            const int col = cb * 16 + fr;
            const f16x8 b = *(const f16x8*)(WTb + col * 256 + (kb ^ ((col & 7) << 4)));
            acc[0][cb] = __builtin_amdgcn_mfma_f32_16x16x32_f16(a0, b, acc[0][cb], 0, 0, 0);
            acc[1][cb] = __builtin_amdgcn_mfma_f32_16x16x32_f16(a1, b, acc[1][cb], 0, 0, 0);
        }
    }

    float b2v[8];
#pragma unroll
    for (int cb = 0; cb < 8; ++cb) b2v[cb] = b2[cb * 16 + fr];
    float s[8], q[8];
#pragma unroll
    for (int cb = 0; cb < 8; ++cb) { s[cb] = 0.f; q[cb] = 0.f; }

#pragma unroll
    for (int rf = 0; rf < 2; ++rf) {
        const int r0 = m0 + w * 32 + rf * 16 + fg * 4;
#pragma unroll
        for (int cb = 0; cb < 8; ++cb) {
            const int col = cb * 16 + fr;
#pragma unroll
            for (int j = 0; j < 4; ++j) {
                const int row = r0 + j;
                if (row < M) {
                    const float v = acc[rf][cb][j] + b2v[cb];
                    h16[(size_t)row * 128 + col] = f2h(v);
                    s[cb] += v;
                    q[cb] += v * v;
                }
            }
        }
    }
#pragma unroll
    for (int cb = 0; cb < 8; ++cb) {
        float ss = s[cb]; ss += __shfl_down(ss, 32); ss += __shfl_down(ss, 16);
        float qq = q[cb]; qq += __shfl_down(qq, 32); qq += __shfl_down(qq, 16);
        if (lane < 16) {
            atomicAdd(&bsum[cb * 16 + lane], ss);
            atomicAdd(&bsum[128 + cb * 16 + lane], qq);
        }
    }
    __syncthreads();
    unsafeAtomicAdd(&sums[tid], bsum[tid]);
}

// ---------------------------------------------------------------------------
__global__ __launch_bounds__(128) void bn_finalize_kernel(
    const float* __restrict__ sums,
    const float* __restrict__ gamma, const float* __restrict__ beta,
    float* __restrict__ scsh, float invM)
{
    const int c = threadIdx.x;
    const float mu  = sums[c] * invM;
    const float var = sums[128 + c] * invM - mu * mu;
    const float sc  = gamma[c] * rsqrtf(var + BN_EPS);
    scsh[c]       = sc;
    scsh[128 + c] = beta[c] - mu * sc;
}

// ---------------------------------------------------------------------------
extern "C" void kernel_launch(void* const* d_in, const int* in_sizes, int n_in,
                              void* d_out, int out_size, void* d_ws, size_t ws_size,
                              hipStream_t stream)
{
    const float* x_in  = (const float*)d_in[0];
    const int*   ei    = (const int*)  d_in[1];
    const float* ea    = (const float*)d_in[2];
    const float* W_lin = (const float*)d_in[3];
    const float* b_lin = (const float*)d_in[4];
    const float* W1    = (const float*)d_in[5];
    const float* b1    = (const float*)d_in[6];
    const float* W2    = (const float*)d_in[7];
    const float* b2    = (const float*)d_in[8];
    const float* gamma = (const float*)d_in[9];
    const float* beta  = (const float*)d_in[10];

    const int N = in_sizes[0] / D_DIM;              // 50000
    const int E = in_sizes[2] / EDGE_DIM;           // 600000
    const int L = in_sizes[3] / (EDGE_DIM * D_DIM); // 3
    const int nchunks = (E + CHUNK - 1) / CHUNK;

    const int* src = ei;
    const int* dst = ei + E;

    float* out = (float*)d_out;

    char* wp = (char*)d_ws;
    auto take = [&wp](size_t bytes) {
        char* r = wp;
        wp += (bytes + 15) & ~(size_t)15;
        return r;
    };
    unsigned*  agg16d  = (unsigned*) take((size_t)N * D_DIM * 2);
    ushort_t*  h16     = (ushort_t*) take((size_t)N * D_DIM * 2);
    unsigned*  x16d    = (unsigned*) take((size_t)N * D_DIM * 2);
    float*     sums    = (float*)    take(256 * 4);
    float*     scsh    = (float*)    take(256 * 4);
    unsigned*  wflin   = (unsigned*) take(2048 * 4);
    int*       cnt     = (int*)      take((size_t)N * 4);
    int*       row_off = (int*)      take((size_t)(N + 1) * 4);
    int*       cur     = (int*)      take((size_t)N * 4);
    int*       blksum  = (int*)      take(256 * 4);
    int*       chunk1  = (int*)      take((size_t)(nchunks + 1) * 4);
    int*       srcs    = (int*)      take((size_t)E * 4);
    uint4*     ea16q   = (uint4*)    take(((size_t)E + ECAP) * 64);

    const int gemmBlocks = (N + 127) / 128;
    const int scanBlocks = (N + 2047) / 2048;

    hipMemsetAsync(cnt, 0, (size_t)N * sizeof(int), stream);
    hipMemsetAsync(chunk1, 0x7f, (size_t)(nchunks + 1) * sizeof(int), stream);
    hist_kernel<<<1024, 256, 0, stream>>>(dst, cnt, E);
    scan_local_kernel<<<scanBlocks, 256, 0, stream>>>(cnt, row_off, blksum, N);
    scan_tops_kernel<<<1, 64, 0, stream>>>(blksum, row_off, N, scanBlocks);
    scan_add_kernel<<<scanBlocks, 256, 0, stream>>>(row_off, cur, blksum, N);
    chunk_first_kernel<<<(N + 255) / 256, 256, 0, stream>>>(row_off, chunk1, N, nchunks);
    scatter_conv_kernel<<<1024, 256, 0, stream>>>(src, dst, ea, cur, srcs, ea16q, E);

    for (int l = 0; l < L; ++l) {
        hipMemsetAsync(sums, 0, 256 * sizeof(float), stream);

        const float* Wl_l = W_lin + (size_t)l * EDGE_DIM * D_DIM;
        const float* bl_l = b_lin + (size_t)l * D_DIM;
        const float* W1_l = W1 + (size_t)l * D_DIM * D_DIM;
        const float* b1_l = b1 + (size_t)l * D_DIM;
        const float* W2_l = W2 + (size_t)l * D_DIM * D_DIM;
        const float* b2_l = b2 + (size_t)l * D_DIM;

        if (l == 0)
            xprep0_kernel<<<1024, 256, 0, stream>>>(x_in, (uint2*)x16d, N);
        else
            apply_kernel<0><<<1024, 256, 0, stream>>>(h16, scsh, (uint2*)x16d, nullptr, N);

        wlin_build_kernel<<<8, 256, 0, stream>>>(Wl_l, wflin);

        fused_edge_kernel<<<nchunks, 256, 0, stream>>>(
            x16d, srcs, (const ushort_t*)ea16q, (const ushort_t*)wflin,
            bl_l, row_off, chunk1, agg16d, N);

        fused_mlp_kernel<<<gemmBlocks, 256, 0, stream>>>(
            agg16d, W1_l, b1_l, W2_l, b2_l, h16, sums, N);

        bn_finalize_kernel<<<1, 128, 0, stream>>>(
            sums, gamma + (size_t)l * D_DIM, beta + (size_t)l * D_DIM,
            scsh, 1.f / (float)N);
    }

    apply_kernel<1><<<1024, 256, 0, stream>>>(h16, scsh, nullptr, out, N);
}

// Round 15
// 420.110 us; speedup vs baseline: 1.0972x; 1.0641x over previous
//
#include <hip/hip_runtime.h>

#define D_DIM 128
#define EDGE_DIM 32
#define BN_EPS 1e-5f

typedef __attribute__((ext_vector_type(8))) _Float16 f16x8;
typedef __attribute__((ext_vector_type(2))) _Float16 half2v;
typedef __attribute__((ext_vector_type(4))) float f32x4;
typedef unsigned short ushort_t;

__device__ __forceinline__ unsigned short f2h(float f) {
    union { _Float16 h; unsigned short u; } c;
    c.h = (_Float16)f;
    return c.u;
}
__device__ __forceinline__ unsigned pk2h(float lo, float hi) {
    return (unsigned)f2h(lo) | ((unsigned)f2h(hi) << 16);
}
__device__ __forceinline__ half2v asH2(unsigned u) {
    union { unsigned u; half2v h; } c;
    c.u = u;
    return c.h;
}
__device__ __forceinline__ float fdot2f(half2v a, half2v b, float c) {
#if __has_builtin(__builtin_amdgcn_fdot2)
    return __builtin_amdgcn_fdot2(a, b, c, false);
#else
    return c + (float)a.x * (float)b.x + (float)a.y * (float)b.y;
#endif
}

// ---------------------------------------------------------------------------
// CSR build: histogram -> multi-block scan -> scatter(+fp16 convert)
// ---------------------------------------------------------------------------
__global__ __launch_bounds__(256) void hist_kernel(
    const int* __restrict__ dst, int* __restrict__ cnt, int E)
{
    for (int e = blockIdx.x * 256 + threadIdx.x; e < E; e += gridDim.x * 256)
        atomicAdd(&cnt[dst[e]], 1);
}

__global__ __launch_bounds__(256) void scan_local_kernel(
    const int* __restrict__ cnt, int* __restrict__ off,
    int* __restrict__ blksum, int n)
{
    __shared__ int part[256];
    const int t = threadIdx.x;
    const int base = blockIdx.x * 2048 + t * 8;
    int v[8];
    int s = 0;
#pragma unroll
    for (int j = 0; j < 8; ++j) {
        const int idx = base + j;
        const int c = (idx < n) ? cnt[idx] : 0;
        v[j] = s;
        s += c;
    }
    part[t] = s;
    __syncthreads();
    for (int d = 1; d < 256; d <<= 1) {
        const int val = (t >= d) ? part[t - d] : 0;
        __syncthreads();
        part[t] += val;
        __syncthreads();
    }
    const int texcl = (t > 0) ? part[t - 1] : 0;
#pragma unroll
    for (int j = 0; j < 8; ++j) {
        const int idx = base + j;
        if (idx < n) off[idx] = texcl + v[j];
    }
    if (t == 255) blksum[blockIdx.x] = part[255];
}

__global__ __launch_bounds__(64) void scan_tops_kernel(
    int* __restrict__ blksum, int* __restrict__ off, int n, int B)
{
    if (threadIdx.x == 0) {
        int run = 0;
        for (int b = 0; b < B; ++b) {
            const int v = blksum[b];
            blksum[b] = run;
            run += v;
        }
        off[n] = run;
    }
}

__global__ __launch_bounds__(256) void scan_add_kernel(
    int* __restrict__ off, int* __restrict__ cur,
    const int* __restrict__ blksum, int n)
{
    const int base = blockIdx.x * 2048;
    const int add = blksum[blockIdx.x];
    for (int j = threadIdx.x; j < 2048; j += 256) {
        const int i = base + j;
        if (i < n) {
            const int v = off[i] + add;
            off[i] = v;
            cur[i] = v;
        }
    }
}

// scatter + inline edge_attr fp16 conversion into CSR order
__global__ __launch_bounds__(256) void scatter_conv_kernel(
    const int* __restrict__ src, const int* __restrict__ dst,
    const float* __restrict__ ea,
    int* __restrict__ cur, int* __restrict__ srcs,
    uint4* __restrict__ ea16q, int E)
{
    for (int e = blockIdx.x * 256 + threadIdx.x; e < E; e += gridDim.x * 256) {
        const int p = atomicAdd(&cur[dst[e]], 1);
        srcs[p] = src[e];
        const float* __restrict__ er = ea + (size_t)e * EDGE_DIM;
#pragma unroll
        for (int q = 0; q < 4; ++q) {
            const float4 a = *(const float4*)(er + q * 8);
            const float4 b = *(const float4*)(er + q * 8 + 4);
            uint4 o;
            o.x = pk2h(a.x, a.y); o.y = pk2h(a.z, a.w);
            o.z = pk2h(b.x, b.y); o.w = pk2h(b.z, b.w);
            ea16q[(size_t)p * 4 + q] = o;
        }
    }
}

// ---------------------------------------------------------------------------
// ALL-layer weight prep (one launch):
//   wl3 : W_lin k-pair-packed fp16, per layer 2048 dwords (kp*128 + c)
//   wf13/wf23 : W1/W2 fragment-linear fp16, per layer 8192 dwords
//               (dword i: col=i>>6, kp=i&63 -> pack(W[2kp][col],W[2kp+1][col]))
// ---------------------------------------------------------------------------
__global__ __launch_bounds__(256) void wbuild_all_kernel(
    const float* __restrict__ W_lin, const float* __restrict__ W1,
    const float* __restrict__ W2,
    unsigned* __restrict__ wl3, unsigned* __restrict__ wf13,
    unsigned* __restrict__ wf23)
{
    const int idx = blockIdx.x * 256 + threadIdx.x;
    if (idx >= 3 * 18432) return;
    const int l = idx / 18432;
    const int r = idx % 18432;
    const float* Wl  = W_lin + (size_t)l * EDGE_DIM * D_DIM;
    const float* W1l = W1 + (size_t)l * D_DIM * D_DIM;
    const float* W2l = W2 + (size_t)l * D_DIM * D_DIM;
    if (r < 2048) {
        const int kp = r >> 7, c = r & 127;
        wl3[l * 2048 + r] = pk2h(Wl[(2 * kp) * D_DIM + c], Wl[(2 * kp + 1) * D_DIM + c]);
    } else if (r < 10240) {
        const int i = r - 2048;
        const int col = i >> 6, kp = i & 63;
        wf13[l * 8192 + i] = pk2h(W1l[(2 * kp) * D_DIM + col], W1l[(2 * kp + 1) * D_DIM + col]);
    } else {
        const int i = r - 10240;
        const int col = i >> 6, kp = i & 63;
        wf23[l * 8192 + i] = pk2h(W2l[(2 * kp) * D_DIM + col], W2l[(2 * kp + 1) * D_DIM + col]);
    }
}

// ---------------------------------------------------------------------------
// xprep0: fp32 x -> fp16 x16 (layer 0 only)
// ---------------------------------------------------------------------------
__global__ __launch_bounds__(256) void xprep0_kernel(
    const float* __restrict__ h, uint2* __restrict__ x16q, int M)
{
    const int total = M * 32;
    for (int i = blockIdx.x * 256 + threadIdx.x; i < total; i += gridDim.x * 256) {
        const float4 v = ((const float4*)h)[i];
        uint2 o; o.x = pk2h(v.x, v.y); o.y = pk2h(v.z, v.w);
        x16q[i] = o;
    }
}

// ---------------------------------------------------------------------------
// final apply: out = relu(h16*sc + sh), sc/sh computed in-block from sums.
// ---------------------------------------------------------------------------
__global__ __launch_bounds__(256) void apply_final_kernel(
    const ushort_t* __restrict__ h16, const float* __restrict__ sums,
    const float* __restrict__ gamma, const float* __restrict__ beta,
    float invN, float* __restrict__ outp, int M)
{
    __shared__ float sc[128], sh[128];
    if (threadIdx.x < 128) {
        const int c = threadIdx.x;
        const float mu  = sums[c] * invN;
        const float var = sums[128 + c] * invN - mu * mu;
        const float s   = gamma[c] * rsqrtf(var + BN_EPS);
        sc[c] = s;
        sh[c] = beta[c] - mu * s;
    }
    __syncthreads();
    const int total = M * 32;
    for (int i = blockIdx.x * 256 + threadIdx.x; i < total; i += gridDim.x * 256) {
        const uint2 hv = *(const uint2*)(h16 + (size_t)i * 4);
        const half2v a = asH2(hv.x), b = asH2(hv.y);
        const int c = (i & 31) * 4;
        f32x4 o;
        o[0] = fmaxf(fmaf((float)a.x, sc[c + 0], sh[c + 0]), 0.f);
        o[1] = fmaxf(fmaf((float)a.y, sc[c + 1], sh[c + 1]), 0.f);
        o[2] = fmaxf(fmaf((float)b.x, sc[c + 2], sh[c + 2]), 0.f);
        o[3] = fmaxf(fmaf((float)b.y, sc[c + 3], sh[c + 3]), 0.f);
        *(f32x4*)(outp + (size_t)i * 4) = o;
    }
}

// ---------------------------------------------------------------------------
// Edge aggregation (R12 structure). For XFORM=1 the previous layer's BN+ReLU
// is applied inline to every gathered row (sc/sh derived from sums in regs):
//   x = relu(h*sc + sh);  agg16[n] = fp16( x_n + sum_e relu(x_src + e) )
// ---------------------------------------------------------------------------
template<int XFORM>
__global__ __launch_bounds__(256, 2) void edge_agg_kernel(
    const unsigned* __restrict__ hsrc,     // N x 64 dwords: x16 (l=0) or h16
    const int*      __restrict__ srcs,
    const uint4*    __restrict__ ea16q,
    const int*      __restrict__ row_off,
    const unsigned* __restrict__ wl16d,
    const float*    __restrict__ bl,
    const float*    __restrict__ sums,     // prev layer BN sums (XFORM)
    const float*    __restrict__ gamma,
    const float*    __restrict__ beta,
    float invN,
    unsigned*       __restrict__ agg16d,
    int nNodes)
{
    const int lane = threadIdx.x & 63;
    const int wid  = threadIdx.x >> 6;

    unsigned wA[16], wB[16];
#pragma unroll
    for (int kp = 0; kp < 16; ++kp) {
        const uint2 w2 = *(const uint2*)(wl16d + kp * 128 + 2 * lane);
        wA[kp] = w2.x; wB[kp] = w2.y;
    }
#pragma unroll
    for (int kp = 0; kp < 16; ++kp) {
        asm volatile("" : "+v"(wA[kp]));
        asm volatile("" : "+v"(wB[kp]));
    }
    const float b0 = bl[2 * lane];
    const float b1 = bl[2 * lane + 1];

    float scl0 = 1.f, shl0 = 0.f, scl1 = 1.f, shl1 = 0.f;
    if (XFORM) {
        const int c0 = 2 * lane, c1 = 2 * lane + 1;
        const float mu0 = sums[c0] * invN;
        const float va0 = sums[128 + c0] * invN - mu0 * mu0;
        scl0 = gamma[c0] * rsqrtf(va0 + BN_EPS);
        shl0 = beta[c0] - mu0 * scl0;
        const float mu1 = sums[c1] * invN;
        const float va1 = sums[128 + c1] * invN - mu1 * mu1;
        scl1 = gamma[c1] * rsqrtf(va1 + BN_EPS);
        shl1 = beta[c1] - mu1 * scl1;
    }

    const int stride = gridDim.x * 4;
    for (int node = blockIdx.x * 4 + wid; node < nNodes; node += stride) {
        const int beg = __builtin_amdgcn_readfirstlane(row_off[node]);
        const int end = __builtin_amdgcn_readfirstlane(row_off[node + 1]);
        float acc0 = 0.f, acc1 = 0.f;

        const int nPair = (end - beg) >> 1;
        int j = beg;
        int sA = 0, sB = 0;
        if (nPair > 0) { sA = srcs[j]; sB = srcs[j + 1]; }

#pragma unroll 1
        for (int it = 0; it < nPair; ++it) {
            const unsigned xdA = hsrc[(size_t)sA * 64 + lane];
            const unsigned xdB = hsrc[(size_t)sB * 64 + lane];
            int sA2 = sA, sB2 = sB;
            if (it + 1 < nPair) {
                sA2 = srcs[j + 2];
                sB2 = srcs[j + 3];
            }
            const uint4 a0 = ea16q[(size_t)j * 4 + 0];
            const uint4 a1 = ea16q[(size_t)j * 4 + 1];
            const uint4 a2 = ea16q[(size_t)j * 4 + 2];
            const uint4 a3 = ea16q[(size_t)j * 4 + 3];
            const uint4 c0 = ea16q[(size_t)(j + 1) * 4 + 0];
            const uint4 c1 = ea16q[(size_t)(j + 1) * 4 + 1];
            const uint4 c2 = ea16q[(size_t)(j + 1) * 4 + 2];
            const uint4 c3 = ea16q[(size_t)(j + 1) * 4 + 3];

            const unsigned awA[16] = {a0.x, a0.y, a0.z, a0.w,
                                      a1.x, a1.y, a1.z, a1.w,
                                      a2.x, a2.y, a2.z, a2.w,
                                      a3.x, a3.y, a3.z, a3.w};
            const unsigned awB[16] = {c0.x, c0.y, c0.z, c0.w,
                                      c1.x, c1.y, c1.z, c1.w,
                                      c2.x, c2.y, c2.z, c2.w,
                                      c3.x, c3.y, c3.z, c3.w};
            float pA0 = b0, pA1 = b1, pB0 = b0, pB1 = b1;
            float qA0 = 0.f, qA1 = 0.f, qB0 = 0.f, qB1 = 0.f;
#pragma unroll
            for (int kp = 0; kp < 8; ++kp) {
                pA0 = fdot2f(asH2(awA[kp]), asH2(wA[kp]), pA0);
                pA1 = fdot2f(asH2(awA[kp]), asH2(wB[kp]), pA1);
                pB0 = fdot2f(asH2(awB[kp]), asH2(wA[kp]), pB0);
                pB1 = fdot2f(asH2(awB[kp]), asH2(wB[kp]), pB1);
                qA0 = fdot2f(asH2(awA[kp + 8]), asH2(wA[kp + 8]), qA0);
                qA1 = fdot2f(asH2(awA[kp + 8]), asH2(wB[kp + 8]), qA1);
                qB0 = fdot2f(asH2(awB[kp + 8]), asH2(wA[kp + 8]), qB0);
                qB1 = fdot2f(asH2(awB[kp + 8]), asH2(wB[kp + 8]), qB1);
            }
            const half2v xhA = asH2(xdA);
            const half2v xhB = asH2(xdB);
            float xA0 = (float)xhA.x, xA1 = (float)xhA.y;
            float xB0 = (float)xhB.x, xB1 = (float)xhB.y;
            if (XFORM) {
                xA0 = fmaxf(fmaf(xA0, scl0, shl0), 0.f);
                xA1 = fmaxf(fmaf(xA1, scl1, shl1), 0.f);
                xB0 = fmaxf(fmaf(xB0, scl0, shl0), 0.f);
                xB1 = fmaxf(fmaf(xB1, scl1, shl1), 0.f);
            }
            acc0 += fmaxf(xA0 + pA0 + qA0, 0.f) + fmaxf(xB0 + pB0 + qB0, 0.f);
            acc1 += fmaxf(xA1 + pA1 + qA1, 0.f) + fmaxf(xB1 + pB1 + qB1, 0.f);
            sA = sA2; sB = sB2;
            j += 2;
        }
        if (j < end) {
            const int s = srcs[j];
            const unsigned xd = hsrc[(size_t)s * 64 + lane];
            const uint4 a0 = ea16q[(size_t)j * 4 + 0];
            const uint4 a1 = ea16q[(size_t)j * 4 + 1];
            const uint4 a2 = ea16q[(size_t)j * 4 + 2];
            const uint4 a3 = ea16q[(size_t)j * 4 + 3];
            const unsigned aw[16] = {a0.x, a0.y, a0.z, a0.w,
                                     a1.x, a1.y, a1.z, a1.w,
                                     a2.x, a2.y, a2.z, a2.w,
                                     a3.x, a3.y, a3.z, a3.w};
            float p0 = b0, p1 = b1, q0 = 0.f, q1 = 0.f;
#pragma unroll
            for (int kp = 0; kp < 8; ++kp) {
                p0 = fdot2f(asH2(aw[kp]), asH2(wA[kp]), p0);
                p1 = fdot2f(asH2(aw[kp]), asH2(wB[kp]), p1);
                q0 = fdot2f(asH2(aw[kp + 8]), asH2(wA[kp + 8]), q0);
                q1 = fdot2f(asH2(aw[kp + 8]), asH2(wB[kp + 8]), q1);
            }
            const half2v xh = asH2(xd);
            float x0 = (float)xh.x, x1 = (float)xh.y;
            if (XFORM) {
                x0 = fmaxf(fmaf(x0, scl0, shl0), 0.f);
                x1 = fmaxf(fmaf(x1, scl1, shl1), 0.f);
            }
            acc0 += fmaxf(x0 + p0 + q0, 0.f);
            acc1 += fmaxf(x1 + p1 + q1, 0.f);
        }
        // GIN self-term folded: agg16 = fp16(x_n + sum)
        const half2v xo = asH2(hsrc[(size_t)node * 64 + lane]);
        float x0 = (float)xo.x, x1 = (float)xo.y;
        if (XFORM) {
            x0 = fmaxf(fmaf(x0, scl0, shl0), 0.f);
            x1 = fmaxf(fmaf(x1, scl1, shl1), 0.f);
        }
        agg16d[(size_t)node * 64 + lane] = pk2h(x0 + acc0, x1 + acc1);
    }
}

// ---------------------------------------------------------------------------
// Fused MLP: h16 = (relu(agg16@W1+b1)) @ W2 + b2 (+BN sums).
// A staged once in LDS (32 KB, swizzled, pure fp16 copy). B-fragments read
// directly from global fragment-linear wfrag (L2-hot). 33 KB LDS -> 4 blk/CU.
// ---------------------------------------------------------------------------
__global__ __launch_bounds__(256) void fused_mlp_kernel(
    const unsigned* __restrict__ agg16d,
    const ushort_t* __restrict__ wf1,
    const float* __restrict__ b1,
    const ushort_t* __restrict__ wf2,
    const float* __restrict__ b2,
    ushort_t* __restrict__ h16,
    float* __restrict__ sums,
    int M)
{
    __shared__ char ATb[128 * 256];
    __shared__ float bsum[256];
    const int tid = threadIdx.x;
    const int m0  = blockIdx.x * 128;

    bsum[tid] = 0.f;

    // --- stage A: pure fp16 copy, XOR-swizzled ---
#pragma unroll
    for (int i = 0; i < 8; ++i) {
        const int idx = i * 256 + tid;
        const int r = idx >> 4, c16 = idx & 15;
        const int row = m0 + r;
        uint4 v = make_uint4(0u, 0u, 0u, 0u);
        if (row < M) v = *(const uint4*)(agg16d + (size_t)row * 64 + c16 * 4);
        *(uint4*)(ATb + r * 256 + ((c16 * 16) ^ ((r & 7) << 4))) = v;
    }
    __syncthreads();

    const int lane = tid & 63;
    const int w    = tid >> 6;
    const int fr   = lane & 15;
    const int fg   = lane >> 4;
    const int ar0  = w * 32 + fr;
    const int asz  = (ar0 & 7) << 4;

    f32x4 acc[2][8];
#pragma unroll
    for (int a = 0; a < 2; ++a)
#pragma unroll
        for (int b = 0; b < 8; ++b) acc[a][b] = (f32x4){0.f, 0.f, 0.f, 0.f};

    // --- MFMA 1: B from global wf1 ---
#pragma unroll
    for (int ks = 0; ks < 4; ++ks) {
        const int kb = ks * 64 + fg * 16;
        const f16x8 a0 = *(const f16x8*)(ATb + ar0 * 256 + (kb ^ asz));
        const f16x8 a1 = *(const f16x8*)(ATb + (ar0 + 16) * 256 + (kb ^ asz));
        f16x8 bf[8];
#pragma unroll
        for (int cb = 0; cb < 8; ++cb)
            bf[cb] = *(const f16x8*)(wf1 + (cb * 16 + fr) * 128 + ks * 32 + fg * 8);
#pragma unroll
        for (int cb = 0; cb < 8; ++cb) {
            acc[0][cb] = __builtin_amdgcn_mfma_f32_16x16x32_f16(a0, bf[cb], acc[0][cb], 0, 0, 0);
            acc[1][cb] = __builtin_amdgcn_mfma_f32_16x16x32_f16(a1, bf[cb], acc[1][cb], 0, 0, 0);
        }
    }
    __syncthreads();

    // --- write relu(h1) tile into ATb (fp16, same swizzled layout) ---
    {
        float b1v[8];
#pragma unroll
        for (int cb = 0; cb < 8; ++cb) b1v[cb] = b1[cb * 16 + fr];
#pragma unroll
        for (int rf = 0; rf < 2; ++rf) {
            const int rb = w * 32 + rf * 16 + fg * 4;
#pragma unroll
            for (int cb = 0; cb < 8; ++cb) {
                const int cc = cb * 16 + fr;
#pragma unroll
                for (int j = 0; j < 4; ++j) {
                    const int r = rb + j;
                    const float v = fmaxf(acc[rf][cb][j] + b1v[cb], 0.f);
                    *(ushort_t*)(ATb + r * 256 + ((cc * 2) ^ ((r & 7) << 4))) = f2h(v);
                }
            }
        }
    }
#pragma unroll
    for (int a = 0; a < 2; ++a)
#pragma unroll
        for (int b = 0; b < 8; ++b) acc[a][b] = (f32x4){0.f, 0.f, 0.f, 0.f};
    __syncthreads();

    // --- MFMA 2: B from global wf2 ---
#pragma unroll
    for (int ks = 0; ks < 4; ++ks) {
        const int kb = ks * 64 + fg * 16;
        const f16x8 a0 = *(const f16x8*)(ATb + ar0 * 256 + (kb ^ asz));
        const f16x8 a1 = *(const f16x8*)(ATb + (ar0 + 16) * 256 + (kb ^ asz));
        f16x8 bf[8];
#pragma unroll
        for (int cb = 0; cb < 8; ++cb)
            bf[cb] = *(const f16x8*)(wf2 + (cb * 16 + fr) * 128 + ks * 32 + fg * 8);
#pragma unroll
        for (int cb = 0; cb < 8; ++cb) {
            acc[0][cb] = __builtin_amdgcn_mfma_f32_16x16x32_f16(a0, bf[cb], acc[0][cb], 0, 0, 0);
            acc[1][cb] = __builtin_amdgcn_mfma_f32_16x16x32_f16(a1, bf[cb], acc[1][cb], 0, 0, 0);
        }
    }

    // --- epilogue: bias, BN sums, fp16 h out ---
    float b2v[8];
#pragma unroll
    for (int cb = 0; cb < 8; ++cb) b2v[cb] = b2[cb * 16 + fr];
    float s[8], q[8];
#pragma unroll
    for (int cb = 0; cb < 8; ++cb) { s[cb] = 0.f; q[cb] = 0.f; }

#pragma unroll
    for (int rf = 0; rf < 2; ++rf) {
        const int r0 = m0 + w * 32 + rf * 16 + fg * 4;
#pragma unroll
        for (int cb = 0; cb < 8; ++cb) {
            const int col = cb * 16 + fr;
#pragma unroll
            for (int j = 0; j < 4; ++j) {
                const int row = r0 + j;
                if (row < M) {
                    const float v = acc[rf][cb][j] + b2v[cb];
                    h16[(size_t)row * 128 + col] = f2h(v);
                    s[cb] += v;
                    q[cb] += v * v;
                }
            }
        }
    }
#pragma unroll
    for (int cb = 0; cb < 8; ++cb) {
        float ss = s[cb]; ss += __shfl_down(ss, 32); ss += __shfl_down(ss, 16);
        float qq = q[cb]; qq += __shfl_down(qq, 32); qq += __shfl_down(qq, 16);
        if (lane < 16) {
            atomicAdd(&bsum[cb * 16 + lane], ss);
            atomicAdd(&bsum[128 + cb * 16 + lane], qq);
        }
    }
    __syncthreads();
    unsafeAtomicAdd(&sums[tid], bsum[tid]);
}

// ---------------------------------------------------------------------------
extern "C" void kernel_launch(void* const* d_in, const int* in_sizes, int n_in,
                              void* d_out, int out_size, void* d_ws, size_t ws_size,
                              hipStream_t stream)
{
    const float* x_in  = (const float*)d_in[0];
    const int*   ei    = (const int*)  d_in[1];
    const float* ea    = (const float*)d_in[2];
    const float* W_lin = (const float*)d_in[3];
    const float* b_lin = (const float*)d_in[4];
    const float* W1    = (const float*)d_in[5];
    const float* b1    = (const float*)d_in[6];
    const float* W2    = (const float*)d_in[7];
    const float* b2    = (const float*)d_in[8];
    const float* gamma = (const float*)d_in[9];
    const float* beta  = (const float*)d_in[10];

    const int N = in_sizes[0] / D_DIM;              // 50000
    const int E = in_sizes[2] / EDGE_DIM;           // 600000
    const int L = in_sizes[3] / (EDGE_DIM * D_DIM); // 3
    const float invN = 1.f / (float)N;

    const int* src = ei;
    const int* dst = ei + E;

    float* out = (float*)d_out;

    char* wp = (char*)d_ws;
    auto take = [&wp](size_t bytes) {
        char* r = wp;
        wp += (bytes + 15) & ~(size_t)15;
        return r;
    };
    unsigned*  agg16d  = (unsigned*) take((size_t)N * D_DIM * 2);
    ushort_t*  h16     = (ushort_t*) take((size_t)N * D_DIM * 2);
    unsigned*  x16d    = (unsigned*) take((size_t)N * D_DIM * 2);
    float*     sums3   = (float*)    take(3 * 256 * 4);
    unsigned*  wl3     = (unsigned*) take(3 * 2048 * 4);
    unsigned*  wf13    = (unsigned*) take(3 * 8192 * 4);
    unsigned*  wf23    = (unsigned*) take(3 * 8192 * 4);
    int*       cnt     = (int*)      take((size_t)N * 4);
    int*       row_off = (int*)      take((size_t)(N + 1) * 4);
    int*       cur     = (int*)      take((size_t)N * 4);
    int*       blksum  = (int*)      take(256 * 4);
    int*       srcs    = (int*)      take((size_t)E * 4);
    uint4*     ea16q   = (uint4*)    take((size_t)E * 64);

    const int gemmBlocks = (N + 127) / 128;
    const int scanBlocks = (N + 2047) / 2048;

    // ---- preamble (once per call) ----
    hipMemsetAsync(cnt, 0, (size_t)N * sizeof(int), stream);
    hipMemsetAsync(sums3, 0, 3 * 256 * sizeof(float), stream);
    hist_kernel<<<1024, 256, 0, stream>>>(dst, cnt, E);
    scan_local_kernel<<<scanBlocks, 256, 0, stream>>>(cnt, row_off, blksum, N);
    scan_tops_kernel<<<1, 64, 0, stream>>>(blksum, row_off, N, scanBlocks);
    scan_add_kernel<<<scanBlocks, 256, 0, stream>>>(row_off, cur, blksum, N);
    scatter_conv_kernel<<<1024, 256, 0, stream>>>(src, dst, ea, cur, srcs, ea16q, E);
    wbuild_all_kernel<<<216, 256, 0, stream>>>(W_lin, W1, W2, wl3, wf13, wf23);
    xprep0_kernel<<<1024, 256, 0, stream>>>(x_in, (uint2*)x16d, N);

    // ---- layers: 2 launches each ----
    for (int l = 0; l < L; ++l) {
        const float* bl_l = b_lin + (size_t)l * D_DIM;
        const float* b1_l = b1 + (size_t)l * D_DIM;
        const float* b2_l = b2 + (size_t)l * D_DIM;
        const unsigned* wl_l = wl3 + (size_t)l * 2048;
        const ushort_t* wf1_l = (const ushort_t*)(wf13 + (size_t)l * 8192);
        const ushort_t* wf2_l = (const ushort_t*)(wf23 + (size_t)l * 8192);

        if (l == 0) {
            edge_agg_kernel<0><<<2048, 256, 0, stream>>>(
                x16d, srcs, ea16q, row_off, wl_l, bl_l,
                nullptr, nullptr, nullptr, invN, agg16d, N);
        } else {
            edge_agg_kernel<1><<<2048, 256, 0, stream>>>(
                (const unsigned*)h16, srcs, ea16q, row_off, wl_l, bl_l,
                sums3 + (size_t)(l - 1) * 256,
                gamma + (size_t)(l - 1) * D_DIM,
                beta + (size_t)(l - 1) * D_DIM, invN, agg16d, N);
        }

        fused_mlp_kernel<<<gemmBlocks, 256, 0, stream>>>(
            agg16d, wf1_l, b1_l, wf2_l, b2_l, h16,
            sums3 + (size_t)l * 256, N);
    }

    apply_final_kernel<<<1024, 256, 0, stream>>>(
        h16, sums3 + 2 * 256, gamma + 2 * D_DIM, beta + 2 * D_DIM,
        invN, out, N);
}

// Round 16
// 416.081 us; speedup vs baseline: 1.1078x; 1.0097x over previous
//
#include <hip/hip_runtime.h>

#define D_DIM 128
#define EDGE_DIM 32
#define BN_EPS 1e-5f

typedef __attribute__((ext_vector_type(8))) _Float16 f16x8;
typedef __attribute__((ext_vector_type(2))) _Float16 half2v;
typedef __attribute__((ext_vector_type(4))) float f32x4;
typedef unsigned short ushort_t;

__device__ __forceinline__ unsigned short f2h(float f) {
    union { _Float16 h; unsigned short u; } c;
    c.h = (_Float16)f;
    return c.u;
}
__device__ __forceinline__ unsigned pk2h(float lo, float hi) {
    return (unsigned)f2h(lo) | ((unsigned)f2h(hi) << 16);
}
__device__ __forceinline__ half2v asH2(unsigned u) {
    union { unsigned u; half2v h; } c;
    c.u = u;
    return c.h;
}
__device__ __forceinline__ float fdot2f(half2v a, half2v b, float c) {
#if __has_builtin(__builtin_amdgcn_fdot2)
    return __builtin_amdgcn_fdot2(a, b, c, false);
#else
    return c + (float)a.x * (float)b.x + (float)a.y * (float)b.y;
#endif
}

// ---------------------------------------------------------------------------
// CSR build: histogram -> multi-block scan -> scatter(+fp16 convert)
// ---------------------------------------------------------------------------
__global__ __launch_bounds__(256) void hist_kernel(
    const int* __restrict__ dst, int* __restrict__ cnt, int E)
{
    for (int e = blockIdx.x * 256 + threadIdx.x; e < E; e += gridDim.x * 256)
        atomicAdd(&cnt[dst[e]], 1);
}

__global__ __launch_bounds__(256) void scan_local_kernel(
    const int* __restrict__ cnt, int* __restrict__ off,
    int* __restrict__ blksum, int n)
{
    __shared__ int part[256];
    const int t = threadIdx.x;
    const int base = blockIdx.x * 2048 + t * 8;
    int v[8];
    int s = 0;
#pragma unroll
    for (int j = 0; j < 8; ++j) {
        const int idx = base + j;
        const int c = (idx < n) ? cnt[idx] : 0;
        v[j] = s;
        s += c;
    }
    part[t] = s;
    __syncthreads();
    for (int d = 1; d < 256; d <<= 1) {
        const int val = (t >= d) ? part[t - d] : 0;
        __syncthreads();
        part[t] += val;
        __syncthreads();
    }
    const int texcl = (t > 0) ? part[t - 1] : 0;
#pragma unroll
    for (int j = 0; j < 8; ++j) {
        const int idx = base + j;
        if (idx < n) off[idx] = texcl + v[j];
    }
    if (t == 255) blksum[blockIdx.x] = part[255];
}

__global__ __launch_bounds__(64) void scan_tops_kernel(
    int* __restrict__ blksum, int* __restrict__ off, int n, int B)
{
    if (threadIdx.x == 0) {
        int run = 0;
        for (int b = 0; b < B; ++b) {
            const int v = blksum[b];
            blksum[b] = run;
            run += v;
        }
        off[n] = run;
    }
}

__global__ __launch_bounds__(256) void scan_add_kernel(
    int* __restrict__ off, int* __restrict__ cur,
    const int* __restrict__ blksum, int n)
{
    const int base = blockIdx.x * 2048;
    const int add = blksum[blockIdx.x];
    for (int j = threadIdx.x; j < 2048; j += 256) {
        const int i = base + j;
        if (i < n) {
            const int v = off[i] + add;
            off[i] = v;
            cur[i] = v;
        }
    }
}

// scatter + inline edge_attr fp16 conversion into CSR order
__global__ __launch_bounds__(256) void scatter_conv_kernel(
    const int* __restrict__ src, const int* __restrict__ dst,
    const float* __restrict__ ea,
    int* __restrict__ cur, int* __restrict__ srcs,
    uint4* __restrict__ ea16q, int E)
{
    for (int e = blockIdx.x * 256 + threadIdx.x; e < E; e += gridDim.x * 256) {
        const int p = atomicAdd(&cur[dst[e]], 1);
        srcs[p] = src[e];
        const float* __restrict__ er = ea + (size_t)e * EDGE_DIM;
#pragma unroll
        for (int q = 0; q < 4; ++q) {
            const float4 a = *(const float4*)(er + q * 8);
            const float4 b = *(const float4*)(er + q * 8 + 4);
            uint4 o;
            o.x = pk2h(a.x, a.y); o.y = pk2h(a.z, a.w);
            o.z = pk2h(b.x, b.y); o.w = pk2h(b.z, b.w);
            ea16q[(size_t)p * 4 + q] = o;
        }
    }
}

// ---------------------------------------------------------------------------
// ALL-layer weight prep (one launch):
//   wl3 : W_lin k-pair-packed fp16, per layer 2048 dwords (kp*128 + c)
//   wf13/wf23 : W1/W2 fragment-linear fp16, per layer 8192 dwords
// ---------------------------------------------------------------------------
__global__ __launch_bounds__(256) void wbuild_all_kernel(
    const float* __restrict__ W_lin, const float* __restrict__ W1,
    const float* __restrict__ W2,
    unsigned* __restrict__ wl3, unsigned* __restrict__ wf13,
    unsigned* __restrict__ wf23)
{
    const int idx = blockIdx.x * 256 + threadIdx.x;
    if (idx >= 3 * 18432) return;
    const int l = idx / 18432;
    const int r = idx % 18432;
    const float* Wl  = W_lin + (size_t)l * EDGE_DIM * D_DIM;
    const float* W1l = W1 + (size_t)l * D_DIM * D_DIM;
    const float* W2l = W2 + (size_t)l * D_DIM * D_DIM;
    if (r < 2048) {
        const int kp = r >> 7, c = r & 127;
        wl3[l * 2048 + r] = pk2h(Wl[(2 * kp) * D_DIM + c], Wl[(2 * kp + 1) * D_DIM + c]);
    } else if (r < 10240) {
        const int i = r - 2048;
        const int col = i >> 6, kp = i & 63;
        wf13[l * 8192 + i] = pk2h(W1l[(2 * kp) * D_DIM + col], W1l[(2 * kp + 1) * D_DIM + col]);
    } else {
        const int i = r - 10240;
        const int col = i >> 6, kp = i & 63;
        wf23[l * 8192 + i] = pk2h(W2l[(2 * kp) * D_DIM + col], W2l[(2 * kp + 1) * D_DIM + col]);
    }
}

// ---------------------------------------------------------------------------
// xprep0: fp32 x -> fp16 x16 (layer 0 only)
// ---------------------------------------------------------------------------
__global__ __launch_bounds__(256) void xprep0_kernel(
    const float* __restrict__ h, uint2* __restrict__ x16q, int M)
{
    const int total = M * 32;
    for (int i = blockIdx.x * 256 + threadIdx.x; i < total; i += gridDim.x * 256) {
        const float4 v = ((const float4*)h)[i];
        uint2 o; o.x = pk2h(v.x, v.y); o.y = pk2h(v.z, v.w);
        x16q[i] = o;
    }
}

// ---------------------------------------------------------------------------
// final apply: out = relu(h16*sc + sh), sc/sh computed in-block from sums.
// ---------------------------------------------------------------------------
__global__ __launch_bounds__(256) void apply_final_kernel(
    const ushort_t* __restrict__ h16, const float* __restrict__ sums,
    const float* __restrict__ gamma, const float* __restrict__ beta,
    float invN, float* __restrict__ outp, int M)
{
    __shared__ float sc[128], sh[128];
    if (threadIdx.x < 128) {
        const int c = threadIdx.x;
        const float mu  = sums[c] * invN;
        const float var = sums[128 + c] * invN - mu * mu;
        const float s   = gamma[c] * rsqrtf(var + BN_EPS);
        sc[c] = s;
        sh[c] = beta[c] - mu * s;
    }
    __syncthreads();
    const int total = M * 32;
    for (int i = blockIdx.x * 256 + threadIdx.x; i < total; i += gridDim.x * 256) {
        const uint2 hv = *(const uint2*)(h16 + (size_t)i * 4);
        const half2v a = asH2(hv.x), b = asH2(hv.y);
        const int c = (i & 31) * 4;
        f32x4 o;
        o[0] = fmaxf(fmaf((float)a.x, sc[c + 0], sh[c + 0]), 0.f);
        o[1] = fmaxf(fmaf((float)a.y, sc[c + 1], sh[c + 1]), 0.f);
        o[2] = fmaxf(fmaf((float)b.x, sc[c + 2], sh[c + 2]), 0.f);
        o[3] = fmaxf(fmaf((float)b.y, sc[c + 3], sh[c + 3]), 0.f);
        *(f32x4*)(outp + (size_t)i * 4) = o;
    }
}

// ---------------------------------------------------------------------------
// Edge aggregation (R15 structure). W_lin staged in LDS: each W access is a
// single ds_read_b64 (one base VGPR + 16-bit imm offset), freeing the vector
// memory queue for x-gathers and eliminating 64-bit global reload addressing.
// ---------------------------------------------------------------------------
template<int XFORM>
__global__ __launch_bounds__(256, 2) void edge_agg_kernel(
    const unsigned* __restrict__ hsrc,     // N x 64 dwords: x16 (l=0) or h16
    const int*      __restrict__ srcs,
    const uint4*    __restrict__ ea16q,
    const int*      __restrict__ row_off,
    const unsigned* __restrict__ wl16d,
    const float*    __restrict__ bl,
    const float*    __restrict__ sums,     // prev layer BN sums (XFORM)
    const float*    __restrict__ gamma,
    const float*    __restrict__ beta,
    float invN,
    unsigned*       __restrict__ agg16d,
    int nNodes)
{
    __shared__ unsigned wlds[2048];        // 8 KB: W_lin k-pair fp16
    const int lane = threadIdx.x & 63;
    const int wid  = threadIdx.x >> 6;

    // stage W_lin into LDS once per block
#pragma unroll
    for (int i = 0; i < 8; ++i)
        wlds[i * 256 + threadIdx.x] = wl16d[i * 256 + threadIdx.x];
    __syncthreads();

    // per-lane W columns: LDS address = lane*8 dwords + kp*512B imm offset
    const unsigned* __restrict__ wl = &wlds[2 * lane];

    const float b0 = bl[2 * lane];
    const float b1 = bl[2 * lane + 1];

    float scl0 = 1.f, shl0 = 0.f, scl1 = 1.f, shl1 = 0.f;
    if (XFORM) {
        const int c0 = 2 * lane, c1 = 2 * lane + 1;
        const float mu0 = sums[c0] * invN;
        const float va0 = sums[128 + c0] * invN - mu0 * mu0;
        scl0 = gamma[c0] * rsqrtf(va0 + BN_EPS);
        shl0 = beta[c0] - mu0 * scl0;
        const float mu1 = sums[c1] * invN;
        const float va1 = sums[128 + c1] * invN - mu1 * mu1;
        scl1 = gamma[c1] * rsqrtf(va1 + BN_EPS);
        shl1 = beta[c1] - mu1 * scl1;
    }

    const int stride = gridDim.x * 4;
    for (int node = blockIdx.x * 4 + wid; node < nNodes; node += stride) {
        const int beg = __builtin_amdgcn_readfirstlane(row_off[node]);
        const int end = __builtin_amdgcn_readfirstlane(row_off[node + 1]);
        float acc0 = 0.f, acc1 = 0.f;

        const int nPair = (end - beg) >> 1;
        int j = beg;
        int sA = 0, sB = 0;
        if (nPair > 0) { sA = srcs[j]; sB = srcs[j + 1]; }

#pragma unroll 1
        for (int it = 0; it < nPair; ++it) {
            const unsigned xdA = hsrc[(size_t)sA * 64 + lane];
            const unsigned xdB = hsrc[(size_t)sB * 64 + lane];
            int sA2 = sA, sB2 = sB;
            if (it + 1 < nPair) {
                sA2 = srcs[j + 2];
                sB2 = srcs[j + 3];
            }
            const uint4 a0 = ea16q[(size_t)j * 4 + 0];
            const uint4 a1 = ea16q[(size_t)j * 4 + 1];
            const uint4 a2 = ea16q[(size_t)j * 4 + 2];
            const uint4 a3 = ea16q[(size_t)j * 4 + 3];
            const uint4 c0 = ea16q[(size_t)(j + 1) * 4 + 0];
            const uint4 c1 = ea16q[(size_t)(j + 1) * 4 + 1];
            const uint4 c2 = ea16q[(size_t)(j + 1) * 4 + 2];
            const uint4 c3 = ea16q[(size_t)(j + 1) * 4 + 3];

            const unsigned awA[16] = {a0.x, a0.y, a0.z, a0.w,
                                      a1.x, a1.y, a1.z, a1.w,
                                      a2.x, a2.y, a2.z, a2.w,
                                      a3.x, a3.y, a3.z, a3.w};
            const unsigned awB[16] = {c0.x, c0.y, c0.z, c0.w,
                                      c1.x, c1.y, c1.z, c1.w,
                                      c2.x, c2.y, c2.z, c2.w,
                                      c3.x, c3.y, c3.z, c3.w};
            float pA0 = b0, pA1 = b1, pB0 = b0, pB1 = b1;
            float qA0 = 0.f, qA1 = 0.f, qB0 = 0.f, qB1 = 0.f;
#pragma unroll
            for (int kp = 0; kp < 8; ++kp) {
                const uint2 wlo = *(const uint2*)&wl[kp * 128];
                const uint2 whi = *(const uint2*)&wl[(kp + 8) * 128];
                pA0 = fdot2f(asH2(awA[kp]), asH2(wlo.x), pA0);
                pA1 = fdot2f(asH2(awA[kp]), asH2(wlo.y), pA1);
                pB0 = fdot2f(asH2(awB[kp]), asH2(wlo.x), pB0);
                pB1 = fdot2f(asH2(awB[kp]), asH2(wlo.y), pB1);
                qA0 = fdot2f(asH2(awA[kp + 8]), asH2(whi.x), qA0);
                qA1 = fdot2f(asH2(awA[kp + 8]), asH2(whi.y), qA1);
                qB0 = fdot2f(asH2(awB[kp + 8]), asH2(whi.x), qB0);
                qB1 = fdot2f(asH2(awB[kp + 8]), asH2(whi.y), qB1);
            }
            const half2v xhA = asH2(xdA);
            const half2v xhB = asH2(xdB);
            float xA0 = (float)xhA.x, xA1 = (float)xhA.y;
            float xB0 = (float)xhB.x, xB1 = (float)xhB.y;
            if (XFORM) {
                xA0 = fmaxf(fmaf(xA0, scl0, shl0), 0.f);
                xA1 = fmaxf(fmaf(xA1, scl1, shl1), 0.f);
                xB0 = fmaxf(fmaf(xB0, scl0, shl0), 0.f);
                xB1 = fmaxf(fmaf(xB1, scl1, shl1), 0.f);
            }
            acc0 += fmaxf(xA0 + pA0 + qA0, 0.f) + fmaxf(xB0 + pB0 + qB0, 0.f);
            acc1 += fmaxf(xA1 + pA1 + qA1, 0.f) + fmaxf(xB1 + pB1 + qB1, 0.f);
            sA = sA2; sB = sB2;
            j += 2;
        }
        if (j < end) {
            const int s = srcs[j];
            const unsigned xd = hsrc[(size_t)s * 64 + lane];
            const uint4 a0 = ea16q[(size_t)j * 4 + 0];
            const uint4 a1 = ea16q[(size_t)j * 4 + 1];
            const uint4 a2 = ea16q[(size_t)j * 4 + 2];
            const uint4 a3 = ea16q[(size_t)j * 4 + 3];
            const unsigned aw[16] = {a0.x, a0.y, a0.z, a0.w,
                                     a1.x, a1.y, a1.z, a1.w,
                                     a2.x, a2.y, a2.z, a2.w,
                                     a3.x, a3.y, a3.z, a3.w};
            float p0 = b0, p1 = b1, q0 = 0.f, q1 = 0.f;
#pragma unroll
            for (int kp = 0; kp < 8; ++kp) {
                const uint2 wlo = *(const uint2*)&wl[kp * 128];
                const uint2 whi = *(const uint2*)&wl[(kp + 8) * 128];
                p0 = fdot2f(asH2(aw[kp]), asH2(wlo.x), p0);
                p1 = fdot2f(asH2(aw[kp]), asH2(wlo.y), p1);
                q0 = fdot2f(asH2(aw[kp + 8]), asH2(whi.x), q0);
                q1 = fdot2f(asH2(aw[kp + 8]), asH2(whi.y), q1);
            }
            const half2v xh = asH2(xd);
            float x0 = (float)xh.x, x1 = (float)xh.y;
            if (XFORM) {
                x0 = fmaxf(fmaf(x0, scl0, shl0), 0.f);
                x1 = fmaxf(fmaf(x1, scl1, shl1), 0.f);
            }
            acc0 += fmaxf(x0 + p0 + q0, 0.f);
            acc1 += fmaxf(x1 + p1 + q1, 0.f);
        }
        // GIN self-term folded: agg16 = fp16(x_n + sum)
        const half2v xo = asH2(hsrc[(size_t)node * 64 + lane]);
        float x0 = (float)xo.x, x1 = (float)xo.y;
        if (XFORM) {
            x0 = fmaxf(fmaf(x0, scl0, shl0), 0.f);
            x1 = fmaxf(fmaf(x1, scl1, shl1), 0.f);
        }
        agg16d[(size_t)node * 64 + lane] = pk2h(x0 + acc0, x1 + acc1);
    }
}

// ---------------------------------------------------------------------------
// Fused MLP: h16 = (relu(agg16@W1+b1)) @ W2 + b2 (+BN sums).
// A staged once in LDS (32 KB, swizzled, pure fp16 copy). B-fragments read
// directly from global fragment-linear wfrag (L2-hot). 33 KB LDS -> 4 blk/CU.
// ---------------------------------------------------------------------------
__global__ __launch_bounds__(256) void fused_mlp_kernel(
    const unsigned* __restrict__ agg16d,
    const ushort_t* __restrict__ wf1,
    const float* __restrict__ b1,
    const ushort_t* __restrict__ wf2,
    const float* __restrict__ b2,
    ushort_t* __restrict__ h16,
    float* __restrict__ sums,
    int M)
{
    __shared__ char ATb[128 * 256];
    __shared__ float bsum[256];
    const int tid = threadIdx.x;
    const int m0  = blockIdx.x * 128;

    bsum[tid] = 0.f;

    // --- stage A: pure fp16 copy, XOR-swizzled ---
#pragma unroll
    for (int i = 0; i < 8; ++i) {
        const int idx = i * 256 + tid;
        const int r = idx >> 4, c16 = idx & 15;
        const int row = m0 + r;
        uint4 v = make_uint4(0u, 0u, 0u, 0u);
        if (row < M) v = *(const uint4*)(agg16d + (size_t)row * 64 + c16 * 4);
        *(uint4*)(ATb + r * 256 + ((c16 * 16) ^ ((r & 7) << 4))) = v;
    }
    __syncthreads();

    const int lane = tid & 63;
    const int w    = tid >> 6;
    const int fr   = lane & 15;
    const int fg   = lane >> 4;
    const int ar0  = w * 32 + fr;
    const int asz  = (ar0 & 7) << 4;

    f32x4 acc[2][8];
#pragma unroll
    for (int a = 0; a < 2; ++a)
#pragma unroll
        for (int b = 0; b < 8; ++b) acc[a][b] = (f32x4){0.f, 0.f, 0.f, 0.f};

    // --- MFMA 1: B from global wf1 ---
#pragma unroll
    for (int ks = 0; ks < 4; ++ks) {
        const int kb = ks * 64 + fg * 16;
        const f16x8 a0 = *(const f16x8*)(ATb + ar0 * 256 + (kb ^ asz));
        const f16x8 a1 = *(const f16x8*)(ATb + (ar0 + 16) * 256 + (kb ^ asz));
        f16x8 bf[8];
#pragma unroll
        for (int cb = 0; cb < 8; ++cb)
            bf[cb] = *(const f16x8*)(wf1 + (cb * 16 + fr) * 128 + ks * 32 + fg * 8);
#pragma unroll
        for (int cb = 0; cb < 8; ++cb) {
            acc[0][cb] = __builtin_amdgcn_mfma_f32_16x16x32_f16(a0, bf[cb], acc[0][cb], 0, 0, 0);
            acc[1][cb] = __builtin_amdgcn_mfma_f32_16x16x32_f16(a1, bf[cb], acc[1][cb], 0, 0, 0);
        }
    }
    __syncthreads();

    // --- write relu(h1) tile into ATb (fp16, same swizzled layout) ---
    {
        float b1v[8];
#pragma unroll
        for (int cb = 0; cb < 8; ++cb) b1v[cb] = b1[cb * 16 + fr];
#pragma unroll
        for (int rf = 0; rf < 2; ++rf) {
            const int rb = w * 32 + rf * 16 + fg * 4;
#pragma unroll
            for (int cb = 0; cb < 8; ++cb) {
                const int cc = cb * 16 + fr;
#pragma unroll
                for (int j = 0; j < 4; ++j) {
                    const int r = rb + j;
                    const float v = fmaxf(acc[rf][cb][j] + b1v[cb], 0.f);
                    *(ushort_t*)(ATb + r * 256 + ((cc * 2) ^ ((r & 7) << 4))) = f2h(v);
                }
            }
        }
    }
#pragma unroll
    for (int a = 0; a < 2; ++a)
#pragma unroll
        for (int b = 0; b < 8; ++b) acc[a][b] = (f32x4){0.f, 0.f, 0.f, 0.f};
    __syncthreads();

    // --- MFMA 2: B from global wf2 ---
#pragma unroll
    for (int ks = 0; ks < 4; ++ks) {
        const int kb = ks * 64 + fg * 16;
        const f16x8 a0 = *(const f16x8*)(ATb + ar0 * 256 + (kb ^ asz));
        const f16x8 a1 = *(const f16x8*)(ATb + (ar0 + 16) * 256 + (kb ^ asz));
        f16x8 bf[8];
#pragma unroll
        for (int cb = 0; cb < 8; ++cb)
            bf[cb] = *(const f16x8*)(wf2 + (cb * 16 + fr) * 128 + ks * 32 + fg * 8);
#pragma unroll
        for (int cb = 0; cb < 8; ++cb) {
            acc[0][cb] = __builtin_amdgcn_mfma_f32_16x16x32_f16(a0, bf[cb], acc[0][cb], 0, 0, 0);
            acc[1][cb] = __builtin_amdgcn_mfma_f32_16x16x32_f16(a1, bf[cb], acc[1][cb], 0, 0, 0);
        }
    }

    // --- epilogue: bias, BN sums, fp16 h out ---
    float b2v[8];
#pragma unroll
    for (int cb = 0; cb < 8; ++cb) b2v[cb] = b2[cb * 16 + fr];
    float s[8], q[8];
#pragma unroll
    for (int cb = 0; cb < 8; ++cb) { s[cb] = 0.f; q[cb] = 0.f; }

#pragma unroll
    for (int rf = 0; rf < 2; ++rf) {
        const int r0 = m0 + w * 32 + rf * 16 + fg * 4;
#pragma unroll
        for (int cb = 0; cb < 8; ++cb) {
            const int col = cb * 16 + fr;
#pragma unroll
            for (int j = 0; j < 4; ++j) {
                const int row = r0 + j;
                if (row < M) {
                    const float v = acc[rf][cb][j] + b2v[cb];
                    h16[(size_t)row * 128 + col] = f2h(v);
                    s[cb] += v;
                    q[cb] += v * v;
                }
            }
        }
    }
#pragma unroll
    for (int cb = 0; cb < 8; ++cb) {
        float ss = s[cb]; ss += __shfl_down(ss, 32); ss += __shfl_down(ss, 16);
        float qq = q[cb]; qq += __shfl_down(qq, 32); qq += __shfl_down(qq, 16);
        if (lane < 16) {
            atomicAdd(&bsum[cb * 16 + lane], ss);
            atomicAdd(&bsum[128 + cb * 16 + lane], qq);
        }
    }
    __syncthreads();
    unsafeAtomicAdd(&sums[tid], bsum[tid]);
}

// ---------------------------------------------------------------------------
extern "C" void kernel_launch(void* const* d_in, const int* in_sizes, int n_in,
                              void* d_out, int out_size, void* d_ws, size_t ws_size,
                              hipStream_t stream)
{
    const float* x_in  = (const float*)d_in[0];
    const int*   ei    = (const int*)  d_in[1];
    const float* ea    = (const float*)d_in[2];
    const float* W_lin = (const float*)d_in[3];
    const float* b_lin = (const float*)d_in[4];
    const float* W1    = (const float*)d_in[5];
    const float* b1    = (const float*)d_in[6];
    const float* W2    = (const float*)d_in[7];
    const float* b2    = (const float*)d_in[8];
    const float* gamma = (const float*)d_in[9];
    const float* beta  = (const float*)d_in[10];

    const int N = in_sizes[0] / D_DIM;              // 50000
    const int E = in_sizes[2] / EDGE_DIM;           // 600000
    const int L = in_sizes[3] / (EDGE_DIM * D_DIM); // 3
    const float invN = 1.f / (float)N;

    const int* src = ei;
    const int* dst = ei + E;

    float* out = (float*)d_out;

    char* wp = (char*)d_ws;
    auto take = [&wp](size_t bytes) {
        char* r = wp;
        wp += (bytes + 15) & ~(size_t)15;
        return r;
    };
    unsigned*  agg16d  = (unsigned*) take((size_t)N * D_DIM * 2);
    ushort_t*  h16     = (ushort_t*) take((size_t)N * D_DIM * 2);
    unsigned*  x16d    = (unsigned*) take((size_t)N * D_DIM * 2);
    float*     sums3   = (float*)    take(3 * 256 * 4);
    unsigned*  wl3     = (unsigned*) take(3 * 2048 * 4);
    unsigned*  wf13    = (unsigned*) take(3 * 8192 * 4);
    unsigned*  wf23    = (unsigned*) take(3 * 8192 * 4);
    int*       cnt     = (int*)      take((size_t)N * 4);
    int*       row_off = (int*)      take((size_t)(N + 1) * 4);
    int*       cur     = (int*)      take((size_t)N * 4);
    int*       blksum  = (int*)      take(256 * 4);
    int*       srcs    = (int*)      take((size_t)E * 4);
    uint4*     ea16q   = (uint4*)    take((size_t)E * 64);

    const int gemmBlocks = (N + 127) / 128;
    const int scanBlocks = (N + 2047) / 2048;

    // ---- preamble (once per call) ----
    hipMemsetAsync(cnt, 0, (size_t)N * sizeof(int), stream);
    hipMemsetAsync(sums3, 0, 3 * 256 * sizeof(float), stream);
    hist_kernel<<<1024, 256, 0, stream>>>(dst, cnt, E);
    scan_local_kernel<<<scanBlocks, 256, 0, stream>>>(cnt, row_off, blksum, N);
    scan_tops_kernel<<<1, 64, 0, stream>>>(blksum, row_off, N, scanBlocks);
    scan_add_kernel<<<scanBlocks, 256, 0, stream>>>(row_off, cur, blksum, N);
    scatter_conv_kernel<<<1024, 256, 0, stream>>>(src, dst, ea, cur, srcs, ea16q, E);
    wbuild_all_kernel<<<216, 256, 0, stream>>>(W_lin, W1, W2, wl3, wf13, wf23);
    xprep0_kernel<<<1024, 256, 0, stream>>>(x_in, (uint2*)x16d, N);

    // ---- layers: 2 launches each ----
    for (int l = 0; l < L; ++l) {
        const float* bl_l = b_lin + (size_t)l * D_DIM;
        const float* b1_l = b1 + (size_t)l * D_DIM;
        const float* b2_l = b2 + (size_t)l * D_DIM;
        const unsigned* wl_l = wl3 + (size_t)l * 2048;
        const ushort_t* wf1_l = (const ushort_t*)(wf13 + (size_t)l * 8192);
        const ushort_t* wf2_l = (const ushort_t*)(wf23 + (size_t)l * 8192);

        if (l == 0) {
            edge_agg_kernel<0><<<2048, 256, 0, stream>>>(
                x16d, srcs, ea16q, row_off, wl_l, bl_l,
                nullptr, nullptr, nullptr, invN, agg16d, N);
        } else {
            edge_agg_kernel<1><<<2048, 256, 0, stream>>>(
                (const unsigned*)h16, srcs, ea16q, row_off, wl_l, bl_l,
                sums3 + (size_t)(l - 1) * 256,
                gamma + (size_t)(l - 1) * D_DIM,
                beta + (size_t)(l - 1) * D_DIM, invN, agg16d, N);
        }

        fused_mlp_kernel<<<gemmBlocks, 256, 0, stream>>>(
            agg16d, wf1_l, b1_l, wf2_l, b2_l, h16,
            sums3 + (size_t)l * 256, N);
    }

    apply_final_kernel<<<1024, 256, 0, stream>>>(
        h16, sums3 + 2 * 256, gamma + 2 * D_DIM, beta + 2 * D_DIM,
        invN, out, N);
}

// Round 17
// 415.425 us; speedup vs baseline: 1.1096x; 1.0016x over previous
//
#include <hip/hip_runtime.h>

#define D_DIM 128
#define EDGE_DIM 32
#define BN_EPS 1e-5f

typedef __attribute__((ext_vector_type(8))) _Float16 f16x8;
typedef __attribute__((ext_vector_type(2))) _Float16 half2v;
typedef __attribute__((ext_vector_type(4))) float f32x4;
typedef unsigned short ushort_t;

__device__ __forceinline__ unsigned short f2h(float f) {
    union { _Float16 h; unsigned short u; } c;
    c.h = (_Float16)f;
    return c.u;
}
__device__ __forceinline__ unsigned pk2h(float lo, float hi) {
    return (unsigned)f2h(lo) | ((unsigned)f2h(hi) << 16);
}
__device__ __forceinline__ half2v asH2(unsigned u) {
    union { unsigned u; half2v h; } c;
    c.u = u;
    return c.h;
}
__device__ __forceinline__ float fdot2f(half2v a, half2v b, float c) {
#if __has_builtin(__builtin_amdgcn_fdot2)
    return __builtin_amdgcn_fdot2(a, b, c, false);
#else
    return c + (float)a.x * (float)b.x + (float)a.y * (float)b.y;
#endif
}

// ---------------------------------------------------------------------------
// CSR build: histogram -> multi-block scan -> scatter(+fp16 convert)
// ---------------------------------------------------------------------------
__global__ __launch_bounds__(256) void hist_kernel(
    const int* __restrict__ dst, int* __restrict__ cnt, int E)
{
    for (int e = blockIdx.x * 256 + threadIdx.x; e < E; e += gridDim.x * 256)
        atomicAdd(&cnt[dst[e]], 1);
}

__global__ __launch_bounds__(256) void scan_local_kernel(
    const int* __restrict__ cnt, int* __restrict__ off,
    int* __restrict__ blksum, int n)
{
    __shared__ int part[256];
    const int t = threadIdx.x;
    const int base = blockIdx.x * 2048 + t * 8;
    int v[8];
    int s = 0;
#pragma unroll
    for (int j = 0; j < 8; ++j) {
        const int idx = base + j;
        const int c = (idx < n) ? cnt[idx] : 0;
        v[j] = s;
        s += c;
    }
    part[t] = s;
    __syncthreads();
    for (int d = 1; d < 256; d <<= 1) {
        const int val = (t >= d) ? part[t - d] : 0;
        __syncthreads();
        part[t] += val;
        __syncthreads();
    }
    const int texcl = (t > 0) ? part[t - 1] : 0;
#pragma unroll
    for (int j = 0; j < 8; ++j) {
        const int idx = base + j;
        if (idx < n) off[idx] = texcl + v[j];
    }
    if (t == 255) blksum[blockIdx.x] = part[255];
}

__global__ __launch_bounds__(64) void scan_tops_kernel(
    int* __restrict__ blksum, int* __restrict__ off, int n, int B)
{
    if (threadIdx.x == 0) {
        int run = 0;
        for (int b = 0; b < B; ++b) {
            const int v = blksum[b];
            blksum[b] = run;
            run += v;
        }
        off[n] = run;
    }
}

__global__ __launch_bounds__(256) void scan_add_kernel(
    int* __restrict__ off, int* __restrict__ cur,
    const int* __restrict__ blksum, int n)
{
    const int base = blockIdx.x * 2048;
    const int add = blksum[blockIdx.x];
    for (int j = threadIdx.x; j < 2048; j += 256) {
        const int i = base + j;
        if (i < n) {
            const int v = off[i] + add;
            off[i] = v;
            cur[i] = v;
        }
    }
}

// scatter + inline edge_attr fp16 conversion into CSR order
__global__ __launch_bounds__(256) void scatter_conv_kernel(
    const int* __restrict__ src, const int* __restrict__ dst,
    const float* __restrict__ ea,
    int* __restrict__ cur, int* __restrict__ srcs,
    uint4* __restrict__ ea16q, int E)
{
    for (int e = blockIdx.x * 256 + threadIdx.x; e < E; e += gridDim.x * 256) {
        const int p = atomicAdd(&cur[dst[e]], 1);
        srcs[p] = src[e];
        const float* __restrict__ er = ea + (size_t)e * EDGE_DIM;
#pragma unroll
        for (int q = 0; q < 4; ++q) {
            const float4 a = *(const float4*)(er + q * 8);
            const float4 b = *(const float4*)(er + q * 8 + 4);
            uint4 o;
            o.x = pk2h(a.x, a.y); o.y = pk2h(a.z, a.w);
            o.z = pk2h(b.x, b.y); o.w = pk2h(b.z, b.w);
            ea16q[(size_t)p * 4 + q] = o;
        }
    }
}

// ---------------------------------------------------------------------------
// ALL-layer weight prep (one launch):
//   wl3 : W_lin k-pair-packed fp16, per layer 2048 dwords (kp*128 + c)
//   wf13/wf23 : W1/W2 fragment-linear fp16, per layer 8192 dwords
// ---------------------------------------------------------------------------
__global__ __launch_bounds__(256) void wbuild_all_kernel(
    const float* __restrict__ W_lin, const float* __restrict__ W1,
    const float* __restrict__ W2,
    unsigned* __restrict__ wl3, unsigned* __restrict__ wf13,
    unsigned* __restrict__ wf23)
{
    const int idx = blockIdx.x * 256 + threadIdx.x;
    if (idx >= 3 * 18432) return;
    const int l = idx / 18432;
    const int r = idx % 18432;
    const float* Wl  = W_lin + (size_t)l * EDGE_DIM * D_DIM;
    const float* W1l = W1 + (size_t)l * D_DIM * D_DIM;
    const float* W2l = W2 + (size_t)l * D_DIM * D_DIM;
    if (r < 2048) {
        const int kp = r >> 7, c = r & 127;
        wl3[l * 2048 + r] = pk2h(Wl[(2 * kp) * D_DIM + c], Wl[(2 * kp + 1) * D_DIM + c]);
    } else if (r < 10240) {
        const int i = r - 2048;
        const int col = i >> 6, kp = i & 63;
        wf13[l * 8192 + i] = pk2h(W1l[(2 * kp) * D_DIM + col], W1l[(2 * kp + 1) * D_DIM + col]);
    } else {
        const int i = r - 10240;
        const int col = i >> 6, kp = i & 63;
        wf23[l * 8192 + i] = pk2h(W2l[(2 * kp) * D_DIM + col], W2l[(2 * kp + 1) * D_DIM + col]);
    }
}

// ---------------------------------------------------------------------------
// xprep0: fp32 x -> fp16 x16 (layer 0 only)
// ---------------------------------------------------------------------------
__global__ __launch_bounds__(256) void xprep0_kernel(
    const float* __restrict__ h, uint2* __restrict__ x16q, int M)
{
    const int total = M * 32;
    for (int i = blockIdx.x * 256 + threadIdx.x; i < total; i += gridDim.x * 256) {
        const float4 v = ((const float4*)h)[i];
        uint2 o; o.x = pk2h(v.x, v.y); o.y = pk2h(v.z, v.w);
        x16q[i] = o;
    }
}

// ---------------------------------------------------------------------------
// final apply: out = relu(h16*sc + sh), sc/sh computed in-block from sums.
// ---------------------------------------------------------------------------
__global__ __launch_bounds__(256) void apply_final_kernel(
    const ushort_t* __restrict__ h16, const float* __restrict__ sums,
    const float* __restrict__ gamma, const float* __restrict__ beta,
    float invN, float* __restrict__ outp, int M)
{
    __shared__ float sc[128], sh[128];
    if (threadIdx.x < 128) {
        const int c = threadIdx.x;
        const float mu  = sums[c] * invN;
        const float var = sums[128 + c] * invN - mu * mu;
        const float s   = gamma[c] * rsqrtf(var + BN_EPS);
        sc[c] = s;
        sh[c] = beta[c] - mu * s;
    }
    __syncthreads();
    const int total = M * 32;
    for (int i = blockIdx.x * 256 + threadIdx.x; i < total; i += gridDim.x * 256) {
        const uint2 hv = *(const uint2*)(h16 + (size_t)i * 4);
        const half2v a = asH2(hv.x), b = asH2(hv.y);
        const int c = (i & 31) * 4;
        f32x4 o;
        o[0] = fmaxf(fmaf((float)a.x, sc[c + 0], sh[c + 0]), 0.f);
        o[1] = fmaxf(fmaf((float)a.y, sc[c + 1], sh[c + 1]), 0.f);
        o[2] = fmaxf(fmaf((float)b.x, sc[c + 2], sh[c + 2]), 0.f);
        o[3] = fmaxf(fmaf((float)b.y, sc[c + 3], sh[c + 3]), 0.f);
        *(f32x4*)(outp + (size_t)i * 4) = o;
    }
}

// ---------------------------------------------------------------------------
// Edge aggregation (R15 structure). W_lin staged in LDS: each W access is a
// single ds_read_b64 (one base VGPR + 16-bit imm offset), freeing the vector
// memory queue for x-gathers and eliminating 64-bit global reload addressing.
// ---------------------------------------------------------------------------
template<int XFORM>
__global__ __launch_bounds__(256, 2) void edge_agg_kernel(
    const unsigned* __restrict__ hsrc,     // N x 64 dwords: x16 (l=0) or h16
    const int*      __restrict__ srcs,
    const uint4*    __restrict__ ea16q,
    const int*      __restrict__ row_off,
    const unsigned* __restrict__ wl16d,
    const float*    __restrict__ bl,
    const float*    __restrict__ sums,     // prev layer BN sums (XFORM)
    const float*    __restrict__ gamma,
    const float*    __restrict__ beta,
    float invN,
    unsigned*       __restrict__ agg16d,
    int nNodes)
{
    __shared__ unsigned wlds[2048];        // 8 KB: W_lin k-pair fp16
    const int lane = threadIdx.x & 63;
    const int wid  = threadIdx.x >> 6;

    // stage W_lin into LDS once per block
#pragma unroll
    for (int i = 0; i < 8; ++i)
        wlds[i * 256 + threadIdx.x] = wl16d[i * 256 + threadIdx.x];
    __syncthreads();

    // per-lane W columns: LDS address = lane*8 dwords + kp*512B imm offset
    const unsigned* __restrict__ wl = &wlds[2 * lane];

    const float b0 = bl[2 * lane];
    const float b1 = bl[2 * lane + 1];

    float scl0 = 1.f, shl0 = 0.f, scl1 = 1.f, shl1 = 0.f;
    if (XFORM) {
        const int c0 = 2 * lane, c1 = 2 * lane + 1;
        const float mu0 = sums[c0] * invN;
        const float va0 = sums[128 + c0] * invN - mu0 * mu0;
        scl0 = gamma[c0] * rsqrtf(va0 + BN_EPS);
        shl0 = beta[c0] - mu0 * scl0;
        const float mu1 = sums[c1] * invN;
        const float va1 = sums[128 + c1] * invN - mu1 * mu1;
        scl1 = gamma[c1] * rsqrtf(va1 + BN_EPS);
        shl1 = beta[c1] - mu1 * scl1;
    }

    const int stride = gridDim.x * 4;
    for (int node = blockIdx.x * 4 + wid; node < nNodes; node += stride) {
        const int beg = __builtin_amdgcn_readfirstlane(row_off[node]);
        const int end = __builtin_amdgcn_readfirstlane(row_off[node + 1]);
        float acc0 = 0.f, acc1 = 0.f;

        const int nPair = (end - beg) >> 1;
        int j = beg;
        int sA = 0, sB = 0;
        if (nPair > 0) { sA = srcs[j]; sB = srcs[j + 1]; }

#pragma unroll 1
        for (int it = 0; it < nPair; ++it) {
            const unsigned xdA = hsrc[(size_t)sA * 64 + lane];
            const unsigned xdB = hsrc[(size_t)sB * 64 + lane];
            int sA2 = sA, sB2 = sB;
            if (it + 1 < nPair) {
                sA2 = srcs[j + 2];
                sB2 = srcs[j + 3];
            }
            const uint4 a0 = ea16q[(size_t)j * 4 + 0];
            const uint4 a1 = ea16q[(size_t)j * 4 + 1];
            const uint4 a2 = ea16q[(size_t)j * 4 + 2];
            const uint4 a3 = ea16q[(size_t)j * 4 + 3];
            const uint4 c0 = ea16q[(size_t)(j + 1) * 4 + 0];
            const uint4 c1 = ea16q[(size_t)(j + 1) * 4 + 1];
            const uint4 c2 = ea16q[(size_t)(j + 1) * 4 + 2];
            const uint4 c3 = ea16q[(size_t)(j + 1) * 4 + 3];

            const unsigned awA[16] = {a0.x, a0.y, a0.z, a0.w,
                                      a1.x, a1.y, a1.z, a1.w,
                                      a2.x, a2.y, a2.z, a2.w,
                                      a3.x, a3.y, a3.z, a3.w};
            const unsigned awB[16] = {c0.x, c0.y, c0.z, c0.w,
                                      c1.x, c1.y, c1.z, c1.w,
                                      c2.x, c2.y, c2.z, c2.w,
                                      c3.x, c3.y, c3.z, c3.w};
            float pA0 = b0, pA1 = b1, pB0 = b0, pB1 = b1;
            float qA0 = 0.f, qA1 = 0.f, qB0 = 0.f, qB1 = 0.f;
#pragma unroll
            for (int kp = 0; kp < 8; ++kp) {
                const uint2 wlo = *(const uint2*)&wl[kp * 128];
                const uint2 whi = *(const uint2*)&wl[(kp + 8) * 128];
                pA0 = fdot2f(asH2(awA[kp]), asH2(wlo.x), pA0);
                pA1 = fdot2f(asH2(awA[kp]), asH2(wlo.y), pA1);
                pB0 = fdot2f(asH2(awB[kp]), asH2(wlo.x), pB0);
                pB1 = fdot2f(asH2(awB[kp]), asH2(wlo.y), pB1);
                qA0 = fdot2f(asH2(awA[kp + 8]), asH2(whi.x), qA0);
                qA1 = fdot2f(asH2(awA[kp + 8]), asH2(whi.y), qA1);
                qB0 = fdot2f(asH2(awB[kp + 8]), asH2(whi.x), qB0);
                qB1 = fdot2f(asH2(awB[kp + 8]), asH2(whi.y), qB1);
            }
            const half2v xhA = asH2(xdA);
            const half2v xhB = asH2(xdB);
            float xA0 = (float)xhA.x, xA1 = (float)xhA.y;
            float xB0 = (float)xhB.x, xB1 = (float)xhB.y;
            if (XFORM) {
                xA0 = fmaxf(fmaf(xA0, scl0, shl0), 0.f);
                xA1 = fmaxf(fmaf(xA1, scl1, shl1), 0.f);
                xB0 = fmaxf(fmaf(xB0, scl0, shl0), 0.f);
                xB1 = fmaxf(fmaf(xB1, scl1, shl1), 0.f);
            }
            acc0 += fmaxf(xA0 + pA0 + qA0, 0.f) + fmaxf(xB0 + pB0 + qB0, 0.f);
            acc1 += fmaxf(xA1 + pA1 + qA1, 0.f) + fmaxf(xB1 + pB1 + qB1, 0.f);
            sA = sA2; sB = sB2;
            j += 2;
        }
        if (j < end) {
            const int s = srcs[j];
            const unsigned xd = hsrc[(size_t)s * 64 + lane];
            const uint4 a0 = ea16q[(size_t)j * 4 + 0];
            const uint4 a1 = ea16q[(size_t)j * 4 + 1];
            const uint4 a2 = ea16q[(size_t)j * 4 + 2];
            const uint4 a3 = ea16q[(size_t)j * 4 + 3];
            const unsigned aw[16] = {a0.x, a0.y, a0.z, a0.w,
                                     a1.x, a1.y, a1.z, a1.w,
                                     a2.x, a2.y, a2.z, a2.w,
                                     a3.x, a3.y, a3.z, a3.w};
            float p0 = b0, p1 = b1, q0 = 0.f, q1 = 0.f;
#pragma unroll
            for (int kp = 0; kp < 8; ++kp) {
                const uint2 wlo = *(const uint2*)&wl[kp * 128];
                const uint2 whi = *(const uint2*)&wl[(kp + 8) * 128];
                p0 = fdot2f(asH2(aw[kp]), asH2(wlo.x), p0);
                p1 = fdot2f(asH2(aw[kp]), asH2(wlo.y), p1);
                q0 = fdot2f(asH2(aw[kp + 8]), asH2(whi.x), q0);
                q1 = fdot2f(asH2(aw[kp + 8]), asH2(whi.y), q1);
            }
            const half2v xh = asH2(xd);
            float x0 = (float)xh.x, x1 = (float)xh.y;
            if (XFORM) {
                x0 = fmaxf(fmaf(x0, scl0, shl0), 0.f);
                x1 = fmaxf(fmaf(x1, scl1, shl1), 0.f);
            }
            acc0 += fmaxf(x0 + p0 + q0, 0.f);
            acc1 += fmaxf(x1 + p1 + q1, 0.f);
        }
        // GIN self-term folded: agg16 = fp16(x_n + sum)
        const half2v xo = asH2(hsrc[(size_t)node * 64 + lane]);
        float x0 = (float)xo.x, x1 = (float)xo.y;
        if (XFORM) {
            x0 = fmaxf(fmaf(x0, scl0, shl0), 0.f);
            x1 = fmaxf(fmaf(x1, scl1, shl1), 0.f);
        }
        agg16d[(size_t)node * 64 + lane] = pk2h(x0 + acc0, x1 + acc1);
    }
}

// ---------------------------------------------------------------------------
// Fused MLP: h16 = (relu(agg16@W1+b1)) @ W2 + b2 (+BN sums).
// A staged once in LDS (32 KB, swizzled, pure fp16 copy). B-fragments read
// directly from global fragment-linear wfrag (L2-hot). 33 KB LDS -> 4 blk/CU.
// ---------------------------------------------------------------------------
__global__ __launch_bounds__(256) void fused_mlp_kernel(
    const unsigned* __restrict__ agg16d,
    const ushort_t* __restrict__ wf1,
    const float* __restrict__ b1,
    const ushort_t* __restrict__ wf2,
    const float* __restrict__ b2,
    ushort_t* __restrict__ h16,
    float* __restrict__ sums,
    int M)
{
    __shared__ char ATb[128 * 256];
    __shared__ float bsum[256];
    const int tid = threadIdx.x;
    const int m0  = blockIdx.x * 128;

    bsum[tid] = 0.f;

    // --- stage A: pure fp16 copy, XOR-swizzled ---
#pragma unroll
    for (int i = 0; i < 8; ++i) {
        const int idx = i * 256 + tid;
        const int r = idx >> 4, c16 = idx & 15;
        const int row = m0 + r;
        uint4 v = make_uint4(0u, 0u, 0u, 0u);
        if (row < M) v = *(const uint4*)(agg16d + (size_t)row * 64 + c16 * 4);
        *(uint4*)(ATb + r * 256 + ((c16 * 16) ^ ((r & 7) << 4))) = v;
    }
    __syncthreads();

    const int lane = tid & 63;
    const int w    = tid >> 6;
    const int fr   = lane & 15;
    const int fg   = lane >> 4;
    const int ar0  = w * 32 + fr;
    const int asz  = (ar0 & 7) << 4;

    f32x4 acc[2][8];
#pragma unroll
    for (int a = 0; a < 2; ++a)
#pragma unroll
        for (int b = 0; b < 8; ++b) acc[a][b] = (f32x4){0.f, 0.f, 0.f, 0.f};

    // --- MFMA 1: B from global wf1 ---
#pragma unroll
    for (int ks = 0; ks < 4; ++ks) {
        const int kb = ks * 64 + fg * 16;
        const f16x8 a0 = *(const f16x8*)(ATb + ar0 * 256 + (kb ^ asz));
        const f16x8 a1 = *(const f16x8*)(ATb + (ar0 + 16) * 256 + (kb ^ asz));
        f16x8 bf[8];
#pragma unroll
        for (int cb = 0; cb < 8; ++cb)
            bf[cb] = *(const f16x8*)(wf1 + (cb * 16 + fr) * 128 + ks * 32 + fg * 8);
#pragma unroll
        for (int cb = 0; cb < 8; ++cb) {
            acc[0][cb] = __builtin_amdgcn_mfma_f32_16x16x32_f16(a0, bf[cb], acc[0][cb], 0, 0, 0);
            acc[1][cb] = __builtin_amdgcn_mfma_f32_16x16x32_f16(a1, bf[cb], acc[1][cb], 0, 0, 0);
        }
    }
    __syncthreads();

    // --- write relu(h1) tile into ATb (fp16, same swizzled layout) ---
    {
        float b1v[8];
#pragma unroll
        for (int cb = 0; cb < 8; ++cb) b1v[cb] = b1[cb * 16 + fr];
#pragma unroll
        for (int rf = 0; rf < 2; ++rf) {
            const int rb = w * 32 + rf * 16 + fg * 4;
#pragma unroll
            for (int cb = 0; cb < 8; ++cb) {
                const int cc = cb * 16 + fr;
#pragma unroll
                for (int j = 0; j < 4; ++j) {
                    const int r = rb + j;
                    const float v = fmaxf(acc[rf][cb][j] + b1v[cb], 0.f);
                    *(ushort_t*)(ATb + r * 256 + ((cc * 2) ^ ((r & 7) << 4))) = f2h(v);
                }
            }
        }
    }
#pragma unroll
    for (int a = 0; a < 2; ++a)
#pragma unroll
        for (int b = 0; b < 8; ++b) acc[a][b] = (f32x4){0.f, 0.f, 0.f, 0.f};
    __syncthreads();

    // --- MFMA 2: B from global wf2 ---
#pragma unroll
    for (int ks = 0; ks < 4; ++ks) {
        const int kb = ks * 64 + fg * 16;
        const f16x8 a0 = *(const f16x8*)(ATb + ar0 * 256 + (kb ^ asz));
        const f16x8 a1 = *(const f16x8*)(ATb + (ar0 + 16) * 256 + (kb ^ asz));
        f16x8 bf[8];
#pragma unroll
        for (int cb = 0; cb < 8; ++cb)
            bf[cb] = *(const f16x8*)(wf2 + (cb * 16 + fr) * 128 + ks * 32 + fg * 8);
#pragma unroll
        for (int cb = 0; cb < 8; ++cb) {
            acc[0][cb] = __builtin_amdgcn_mfma_f32_16x16x32_f16(a0, bf[cb], acc[0][cb], 0, 0, 0);
            acc[1][cb] = __builtin_amdgcn_mfma_f32_16x16x32_f16(a1, bf[cb], acc[1][cb], 0, 0, 0);
        }
    }

    // --- epilogue: bias, BN sums, fp16 h out ---
    float b2v[8];
#pragma unroll
    for (int cb = 0; cb < 8; ++cb) b2v[cb] = b2[cb * 16 + fr];
    float s[8], q[8];
#pragma unroll
    for (int cb = 0; cb < 8; ++cb) { s[cb] = 0.f; q[cb] = 0.f; }

#pragma unroll
    for (int rf = 0; rf < 2; ++rf) {
        const int r0 = m0 + w * 32 + rf * 16 + fg * 4;
#pragma unroll
        for (int cb = 0; cb < 8; ++cb) {
            const int col = cb * 16 + fr;
#pragma unroll
            for (int j = 0; j < 4; ++j) {
                const int row = r0 + j;
                if (row < M) {
                    const float v = acc[rf][cb][j] + b2v[cb];
                    h16[(size_t)row * 128 + col] = f2h(v);
                    s[cb] += v;
                    q[cb] += v * v;
                }
            }
        }
    }
#pragma unroll
    for (int cb = 0; cb < 8; ++cb) {
        float ss = s[cb]; ss += __shfl_down(ss, 32); ss += __shfl_down(ss, 16);
        float qq = q[cb]; qq += __shfl_down(qq, 32); qq += __shfl_down(qq, 16);
        if (lane < 16) {
            atomicAdd(&bsum[cb * 16 + lane], ss);
            atomicAdd(&bsum[128 + cb * 16 + lane], qq);
        }
    }
    __syncthreads();
    unsafeAtomicAdd(&sums[tid], bsum[tid]);
}

// ---------------------------------------------------------------------------
extern "C" void kernel_launch(void* const* d_in, const int* in_sizes, int n_in,
                              void* d_out, int out_size, void* d_ws, size_t ws_size,
                              hipStream_t stream)
{
    const float* x_in  = (const float*)d_in[0];
    const int*   ei    = (const int*)  d_in[1];
    const float* ea    = (const float*)d_in[2];
    const float* W_lin = (const float*)d_in[3];
    const float* b_lin = (const float*)d_in[4];
    const float* W1    = (const float*)d_in[5];
    const float* b1    = (const float*)d_in[6];
    const float* W2    = (const float*)d_in[7];
    const float* b2    = (const float*)d_in[8];
    const float* gamma = (const float*)d_in[9];
    const float* beta  = (const float*)d_in[10];

    const int N = in_sizes[0] / D_DIM;              // 50000
    const int E = in_sizes[2] / EDGE_DIM;           // 600000
    const int L = in_sizes[3] / (EDGE_DIM * D_DIM); // 3
    const float invN = 1.f / (float)N;

    const int* src = ei;
    const int* dst = ei + E;

    float* out = (float*)d_out;

    char* wp = (char*)d_ws;
    auto take = [&wp](size_t bytes) {
        char* r = wp;
        wp += (bytes + 15) & ~(size_t)15;
        return r;
    };
    unsigned*  agg16d  = (unsigned*) take((size_t)N * D_DIM * 2);
    ushort_t*  h16     = (ushort_t*) take((size_t)N * D_DIM * 2);
    unsigned*  x16d    = (unsigned*) take((size_t)N * D_DIM * 2);
    float*     sums3   = (float*)    take(3 * 256 * 4);
    unsigned*  wl3     = (unsigned*) take(3 * 2048 * 4);
    unsigned*  wf13    = (unsigned*) take(3 * 8192 * 4);
    unsigned*  wf23    = (unsigned*) take(3 * 8192 * 4);
    int*       cnt     = (int*)      take((size_t)N * 4);
    int*       row_off = (int*)      take((size_t)(N + 1) * 4);
    int*       cur     = (int*)      take((size_t)N * 4);
    int*       blksum  = (int*)      take(256 * 4);
    int*       srcs    = (int*)      take((size_t)E * 4);
    uint4*     ea16q   = (uint4*)    take((size_t)E * 64);

    const int gemmBlocks = (N + 127) / 128;
    const int scanBlocks = (N + 2047) / 2048;

    // ---- preamble (once per call) ----
    hipMemsetAsync(cnt, 0, (size_t)N * sizeof(int), stream);
    hipMemsetAsync(sums3, 0, 3 * 256 * sizeof(float), stream);
    hist_kernel<<<1024, 256, 0, stream>>>(dst, cnt, E);
    scan_local_kernel<<<scanBlocks, 256, 0, stream>>>(cnt, row_off, blksum, N);
    scan_tops_kernel<<<1, 64, 0, stream>>>(blksum, row_off, N, scanBlocks);
    scan_add_kernel<<<scanBlocks, 256, 0, stream>>>(row_off, cur, blksum, N);
    scatter_conv_kernel<<<1024, 256, 0, stream>>>(src, dst, ea, cur, srcs, ea16q, E);
    wbuild_all_kernel<<<216, 256, 0, stream>>>(W_lin, W1, W2, wl3, wf13, wf23);
    xprep0_kernel<<<1024, 256, 0, stream>>>(x_in, (uint2*)x16d, N);

    // ---- layers: 2 launches each ----
    for (int l = 0; l < L; ++l) {
        const float* bl_l = b_lin + (size_t)l * D_DIM;
        const float* b1_l = b1 + (size_t)l * D_DIM;
        const float* b2_l = b2 + (size_t)l * D_DIM;
        const unsigned* wl_l = wl3 + (size_t)l * 2048;
        const ushort_t* wf1_l = (const ushort_t*)(wf13 + (size_t)l * 8192);
        const ushort_t* wf2_l = (const ushort_t*)(wf23 + (size_t)l * 8192);

        if (l == 0) {
            edge_agg_kernel<0><<<2048, 256, 0, stream>>>(
                x16d, srcs, ea16q, row_off, wl_l, bl_l,
                nullptr, nullptr, nullptr, invN, agg16d, N);
        } else {
            edge_agg_kernel<1><<<2048, 256, 0, stream>>>(
                (const unsigned*)h16, srcs, ea16q, row_off, wl_l, bl_l,
                sums3 + (size_t)(l - 1) * 256,
                gamma + (size_t)(l - 1) * D_DIM,
                beta + (size_t)(l - 1) * D_DIM, invN, agg16d, N);
        }

        fused_mlp_kernel<<<gemmBlocks, 256, 0, stream>>>(
            agg16d, wf1_l, b1_l, wf2_l, b2_l, h16,
            sums3 + (size_t)l * 256, N);
    }

    apply_final_kernel<<<1024, 256, 0, stream>>>(
        h16, sums3 + 2 * 256, gamma + 2 * D_DIM, beta + 2 * D_DIM,
        invN, out, N);
}

// Round 18
// 404.392 us; speedup vs baseline: 1.1399x; 1.0273x over previous
//
#include <hip/hip_runtime.h>

#define D_DIM 128
#define EDGE_DIM 32
#define BN_EPS 1e-5f
#define CHUNK 64
#define ECAP 120

typedef __attribute__((ext_vector_type(8))) _Float16 f16x8;
typedef __attribute__((ext_vector_type(2))) _Float16 half2v;
typedef __attribute__((ext_vector_type(4))) float f32x4;
typedef unsigned short ushort_t;

__device__ __forceinline__ unsigned short f2h(float f) {
    union { _Float16 h; unsigned short u; } c;
    c.h = (_Float16)f;
    return c.u;
}
__device__ __forceinline__ unsigned pk2h(float lo, float hi) {
    return (unsigned)f2h(lo) | ((unsigned)f2h(hi) << 16);
}
__device__ __forceinline__ half2v asH2(unsigned u) {
    union { unsigned u; half2v h; } c;
    c.u = u;
    return c.h;
}

// ---------------------------------------------------------------------------
// CSR build: histogram -> multi-block scan -> scatter(+fp16 convert)
// ---------------------------------------------------------------------------
__global__ __launch_bounds__(256) void hist_kernel(
    const int* __restrict__ dst, int* __restrict__ cnt, int E)
{
    for (int e = blockIdx.x * 256 + threadIdx.x; e < E; e += gridDim.x * 256)
        atomicAdd(&cnt[dst[e]], 1);
}

__global__ __launch_bounds__(256) void scan_local_kernel(
    const int* __restrict__ cnt, int* __restrict__ off,
    int* __restrict__ blksum, int n)
{
    __shared__ int part[256];
    const int t = threadIdx.x;
    const int base = blockIdx.x * 2048 + t * 8;
    int v[8];
    int s = 0;
#pragma unroll
    for (int j = 0; j < 8; ++j) {
        const int idx = base + j;
        const int c = (idx < n) ? cnt[idx] : 0;
        v[j] = s;
        s += c;
    }
    part[t] = s;
    __syncthreads();
    for (int d = 1; d < 256; d <<= 1) {
        const int val = (t >= d) ? part[t - d] : 0;
        __syncthreads();
        part[t] += val;
        __syncthreads();
    }
    const int texcl = (t > 0) ? part[t - 1] : 0;
#pragma unroll
    for (int j = 0; j < 8; ++j) {
        const int idx = base + j;
        if (idx < n) off[idx] = texcl + v[j];
    }
    if (t == 255) blksum[blockIdx.x] = part[255];
}

__global__ __launch_bounds__(64) void scan_tops_kernel(
    int* __restrict__ blksum, int* __restrict__ off, int n, int B)
{
    if (threadIdx.x == 0) {
        int run = 0;
        for (int b = 0; b < B; ++b) {
            const int v = blksum[b];
            blksum[b] = run;
            run += v;
        }
        off[n] = run;
    }
}

__global__ __launch_bounds__(256) void scan_add_kernel(
    int* __restrict__ off, int* __restrict__ cur,
    const int* __restrict__ blksum, int n)
{
    const int base = blockIdx.x * 2048;
    const int add = blksum[blockIdx.x];
    for (int j = threadIdx.x; j < 2048; j += 256) {
        const int i = base + j;
        if (i < n) {
            const int v = off[i] + add;
            off[i] = v;
            cur[i] = v;
        }
    }
}

// scatter + inline edge_attr fp16 conversion into CSR order
__global__ __launch_bounds__(256) void scatter_conv_kernel(
    const int* __restrict__ src, const int* __restrict__ dst,
    const float* __restrict__ ea,
    int* __restrict__ cur, int* __restrict__ srcs,
    uint4* __restrict__ ea16q, int E)
{
    for (int e = blockIdx.x * 256 + threadIdx.x; e < E; e += gridDim.x * 256) {
        const int p = atomicAdd(&cur[dst[e]], 1);
        srcs[p] = src[e];
        const float* __restrict__ er = ea + (size_t)e * EDGE_DIM;
#pragma unroll
        for (int q = 0; q < 4; ++q) {
            const float4 a = *(const float4*)(er + q * 8);
            const float4 b = *(const float4*)(er + q * 8 + 4);
            uint4 o;
            o.x = pk2h(a.x, a.y); o.y = pk2h(a.z, a.w);
            o.z = pk2h(b.x, b.y); o.w = pk2h(b.z, b.w);
            ea16q[(size_t)p * 4 + q] = o;
        }
    }
}

// ---------------------------------------------------------------------------
// chunk_first[c] = first node whose CSR row starts in edge-window c (CHUNK=64).
// chunk_first pre-filled with 0x7f7f7f7f; [nchunks] set to n here.
// ---------------------------------------------------------------------------
__global__ __launch_bounds__(256) void chunk_first_kernel(
    const int* __restrict__ row_off, int* __restrict__ chunk_first,
    int n, int nchunks)
{
    const int i = blockIdx.x * 256 + threadIdx.x;
    if (i == 0) chunk_first[nchunks] = n;
    if (i < n) {
        int c = row_off[i] / CHUNK;
        if (c > nchunks - 1) c = nchunks - 1;
        atomicMin(&chunk_first[c], i);
    }
}

// ---------------------------------------------------------------------------
// ALL-layer weight prep (one launch):
//   wl3 : W_lin MFMA B-fragment layout, per layer 2048 dwords.
//         slot s=cb*64+lane holds 8 halfs W[(lane>>4)*8+j][cb*16+(lane&15)]
//   wf13/wf23 : W1/W2 fragment-linear fp16, per layer 8192 dwords
// ---------------------------------------------------------------------------
__global__ __launch_bounds__(256) void wbuild_all_kernel(
    const float* __restrict__ W_lin, const float* __restrict__ W1,
    const float* __restrict__ W2,
    unsigned* __restrict__ wl3, unsigned* __restrict__ wf13,
    unsigned* __restrict__ wf23)
{
    const int idx = blockIdx.x * 256 + threadIdx.x;
    if (idx >= 3 * 18432) return;
    const int l = idx / 18432;
    const int r = idx % 18432;
    const float* Wl  = W_lin + (size_t)l * EDGE_DIM * D_DIM;
    const float* W1l = W1 + (size_t)l * D_DIM * D_DIM;
    const float* W2l = W2 + (size_t)l * D_DIM * D_DIM;
    if (r < 2048) {
        const int slot = r >> 2, q = r & 3;
        const int cb = slot >> 6, lane = slot & 63;
        const int col = cb * 16 + (lane & 15);
        const int k0 = (lane >> 4) * 8 + 2 * q;
        wl3[l * 2048 + r] = pk2h(Wl[k0 * D_DIM + col], Wl[(k0 + 1) * D_DIM + col]);
    } else if (r < 10240) {
        const int i = r - 2048;
        const int col = i >> 6, kp = i & 63;
        wf13[l * 8192 + i] = pk2h(W1l[(2 * kp) * D_DIM + col], W1l[(2 * kp + 1) * D_DIM + col]);
    } else {
        const int i = r - 10240;
        const int col = i >> 6, kp = i & 63;
        wf23[l * 8192 + i] = pk2h(W2l[(2 * kp) * D_DIM + col], W2l[(2 * kp + 1) * D_DIM + col]);
    }
}

// ---------------------------------------------------------------------------
// xprep0: fp32 x -> fp16 x16 (layer 0 only)
// ---------------------------------------------------------------------------
__global__ __launch_bounds__(256) void xprep0_kernel(
    const float* __restrict__ h, uint2* __restrict__ x16q, int M)
{
    const int total = M * 32;
    for (int i = blockIdx.x * 256 + threadIdx.x; i < total; i += gridDim.x * 256) {
        const float4 v = ((const float4*)h)[i];
        uint2 o; o.x = pk2h(v.x, v.y); o.y = pk2h(v.z, v.w);
        x16q[i] = o;
    }
}

// ---------------------------------------------------------------------------
// final apply: out = relu(h16*sc + sh), sc/sh computed in-block from sums.
// ---------------------------------------------------------------------------
__global__ __launch_bounds__(256) void apply_final_kernel(
    const ushort_t* __restrict__ h16, const float* __restrict__ sums,
    const float* __restrict__ gamma, const float* __restrict__ beta,
    float invN, float* __restrict__ outp, int M)
{
    __shared__ float sc[128], sh[128];
    if (threadIdx.x < 128) {
        const int c = threadIdx.x;
        const float mu  = sums[c] * invN;
        const float var = sums[128 + c] * invN - mu * mu;
        const float s   = gamma[c] * rsqrtf(var + BN_EPS);
        sc[c] = s;
        sh[c] = beta[c] - mu * s;
    }
    __syncthreads();
    const int total = M * 32;
    for (int i = blockIdx.x * 256 + threadIdx.x; i < total; i += gridDim.x * 256) {
        const uint2 hv = *(const uint2*)(h16 + (size_t)i * 4);
        const half2v a = asH2(hv.x), b = asH2(hv.y);
        const int c = (i & 31) * 4;
        f32x4 o;
        o[0] = fmaxf(fmaf((float)a.x, sc[c + 0], sh[c + 0]), 0.f);
        o[1] = fmaxf(fmaf((float)a.y, sc[c + 1], sh[c + 1]), 0.f);
        o[2] = fmaxf(fmaf((float)b.x, sc[c + 2], sh[c + 2]), 0.f);
        o[3] = fmaxf(fmaf((float)b.y, sc[c + 3], sh[c + 3]), 0.f);
        *(f32x4*)(outp + (size_t)i * 4) = o;
    }
}

// ---------------------------------------------------------------------------
// Fused edge pass, node-aligned 64-edge chunks (5 blocks/CU):
//   phase 1: e = ea@W_lin + b_lin via MFMA -> eT[edge][col] fp16 in LDS
//   phase 2: waves split the chunk's nodes; per node batch-4 gather
//            x16[src] (+inline prev BN) + e; plain-store
//            agg16[n] = fp16(x_n + sum relu(...)).  No atomics.
// ---------------------------------------------------------------------------
template<int XFORM>
__global__ __launch_bounds__(256, 5) void fused_edge_kernel(
    const unsigned* __restrict__ hsrc,     // N x 64 dwords: x16 (l=0) or h16
    const int*      __restrict__ srcs,
    const ushort_t* __restrict__ ea16,     // CSR order, padded
    const ushort_t* __restrict__ wflin,    // B-fragment layout, 4096 halfs
    const float*    __restrict__ bl,
    const int*      __restrict__ row_off,
    const int*      __restrict__ chunk_first,
    const float*    __restrict__ sums,     // prev layer BN sums (XFORM)
    const float*    __restrict__ gamma,
    const float*    __restrict__ beta,
    float invN,
    unsigned*       __restrict__ agg16d,
    int nNodes)
{
    __shared__ ushort_t eT[ECAP * 132];
    const int tid  = threadIdx.x;
    const int lane = tid & 63;
    const int w    = tid >> 6;
    const int fr   = lane & 15;
    const int fg   = lane >> 4;
    const int c    = blockIdx.x;

    int nfirst = chunk_first[c];
    int nlast  = chunk_first[c + 1];
    if (nfirst > nNodes) nfirst = nNodes;
    if (nlast  > nNodes) nlast  = nNodes;
    if (nfirst >= nlast) return;      // block-uniform; barrier never reached
    const int ebase = row_off[nfirst];
    const int ecnt  = row_off[nlast] - ebase;

    // ---- phase 1: MFMA e-tile ----
    f16x8 bfr[8];
#pragma unroll
    for (int cb = 0; cb < 8; ++cb)
        bfr[cb] = *(const f16x8*)(wflin + (cb * 64 + lane) * 8);
    float blv[8];
#pragma unroll
    for (int cb = 0; cb < 8; ++cb) blv[cb] = bl[cb * 16 + fr];

    const int rowblocks = (ecnt + 15) >> 4;   // <= ECAP/16 = 8 (ECAP=120 -> 8)
#pragma unroll
    for (int rr = 0; rr < 2; ++rr) {
        const int rb = w + rr * 4;
        if (rb < rowblocks) {
            const f16x8 af = *(const f16x8*)(ea16
                + ((size_t)(ebase + rb * 16 + fr)) * 32 + fg * 8);
            f32x4 acc[8];
#pragma unroll
            for (int cb = 0; cb < 8; ++cb) {
                const f32x4 z = {0.f, 0.f, 0.f, 0.f};
                acc[cb] = __builtin_amdgcn_mfma_f32_16x16x32_f16(af, bfr[cb], z, 0, 0, 0);
            }
#pragma unroll
            for (int cb = 0; cb < 8; ++cb) {
                const int col = cb * 16 + fr;
#pragma unroll
                for (int j = 0; j < 4; ++j) {
                    const int er = rb * 16 + fg * 4 + j;
                    eT[er * 132 + col] = f2h(acc[cb][j] + blv[cb]);
                }
            }
        }
    }
    __syncthreads();

    // ---- phase 2: node-parallel, batch-4 ILP, plain stores ----
    float scl0 = 1.f, shl0 = 0.f, scl1 = 1.f, shl1 = 0.f;
    if (XFORM) {
        const int c0 = 2 * lane, c1 = 2 * lane + 1;
        const float mu0 = sums[c0] * invN;
        const float va0 = sums[128 + c0] * invN - mu0 * mu0;
        scl0 = gamma[c0] * rsqrtf(va0 + BN_EPS);
        shl0 = beta[c0] - mu0 * scl0;
        const float mu1 = sums[c1] * invN;
        const float va1 = sums[128 + c1] * invN - mu1 * mu1;
        scl1 = gamma[c1] * rsqrtf(va1 + BN_EPS);
        shl1 = beta[c1] - mu1 * scl1;
    }

    for (int n = nfirst + w; n < nlast; n += 4) {
        const int beg = __builtin_amdgcn_readfirstlane(row_off[n]);
        const int end = __builtin_amdgcn_readfirstlane(row_off[n + 1]);
        float a0 = 0.f, a1 = 0.f;
        int p = beg;
        const int head = (end - beg) & 3;
#pragma unroll 1
        for (int t = 0; t < head; ++t, ++p) {
            const int s = __builtin_amdgcn_readfirstlane(srcs[p]);
            const unsigned xd = hsrc[(size_t)s * 64 + lane];
            const unsigned ed = *(const unsigned*)&eT[(p - ebase) * 132 + 2 * lane];
            const half2v xh = asH2(xd), eh = asH2(ed);
            float x0 = (float)xh.x, x1 = (float)xh.y;
            if (XFORM) {
                x0 = fmaxf(fmaf(x0, scl0, shl0), 0.f);
                x1 = fmaxf(fmaf(x1, scl1, shl1), 0.f);
            }
            a0 += fmaxf(x0 + (float)eh.x, 0.f);
            a1 += fmaxf(x1 + (float)eh.y, 0.f);
        }
#pragma unroll 1
        for (; p < end; p += 4) {
            const int s0 = __builtin_amdgcn_readfirstlane(srcs[p]);
            const int s1 = __builtin_amdgcn_readfirstlane(srcs[p + 1]);
            const int s2 = __builtin_amdgcn_readfirstlane(srcs[p + 2]);
            const int s3 = __builtin_amdgcn_readfirstlane(srcs[p + 3]);
            const unsigned x0d = hsrc[(size_t)s0 * 64 + lane];
            const unsigned x1d = hsrc[(size_t)s1 * 64 + lane];
            const unsigned x2d = hsrc[(size_t)s2 * 64 + lane];
            const unsigned x3d = hsrc[(size_t)s3 * 64 + lane];
            const int ei = p - ebase;
            const unsigned e0 = *(const unsigned*)&eT[(ei + 0) * 132 + 2 * lane];
            const unsigned e1 = *(const unsigned*)&eT[(ei + 1) * 132 + 2 * lane];
            const unsigned e2 = *(const unsigned*)&eT[(ei + 2) * 132 + 2 * lane];
            const unsigned e3 = *(const unsigned*)&eT[(ei + 3) * 132 + 2 * lane];
#pragma unroll
            for (int t = 0; t < 4; ++t) {
                const unsigned xd = (t == 0) ? x0d : (t == 1) ? x1d : (t == 2) ? x2d : x3d;
                const unsigned ed = (t == 0) ? e0 : (t == 1) ? e1 : (t == 2) ? e2 : e3;
                const half2v xh = asH2(xd), eh = asH2(ed);
                float x0 = (float)xh.x, x1 = (float)xh.y;
                if (XFORM) {
                    x0 = fmaxf(fmaf(x0, scl0, shl0), 0.f);
                    x1 = fmaxf(fmaf(x1, scl1, shl1), 0.f);
                }
                a0 += fmaxf(x0 + (float)eh.x, 0.f);
                a1 += fmaxf(x1 + (float)eh.y, 0.f);
            }
        }
        // GIN self-term folded: agg16 = fp16(x_n + sum)
        const half2v xo = asH2(hsrc[(size_t)n * 64 + lane]);
        float x0 = (float)xo.x, x1 = (float)xo.y;
        if (XFORM) {
            x0 = fmaxf(fmaf(x0, scl0, shl0), 0.f);
            x1 = fmaxf(fmaf(x1, scl1, shl1), 0.f);
        }
        agg16d[(size_t)n * 64 + lane] = pk2h(x0 + a0, x1 + a1);
    }
}

// ---------------------------------------------------------------------------
// Fused MLP: h16 = (relu(agg16@W1+b1)) @ W2 + b2 (+BN sums).
// A staged once in LDS (32 KB, swizzled, pure fp16 copy). B-fragments read
// directly from global fragment-linear wfrag (L2-hot). 33 KB LDS -> 4 blk/CU.
// ---------------------------------------------------------------------------
__global__ __launch_bounds__(256) void fused_mlp_kernel(
    const unsigned* __restrict__ agg16d,
    const ushort_t* __restrict__ wf1,
    const float* __restrict__ b1,
    const ushort_t* __restrict__ wf2,
    const float* __restrict__ b2,
    ushort_t* __restrict__ h16,
    float* __restrict__ sums,
    int M)
{
    __shared__ char ATb[128 * 256];
    __shared__ float bsum[256];
    const int tid = threadIdx.x;
    const int m0  = blockIdx.x * 128;

    bsum[tid] = 0.f;

    // --- stage A: pure fp16 copy, XOR-swizzled ---
#pragma unroll
    for (int i = 0; i < 8; ++i) {
        const int idx = i * 256 + tid;
        const int r = idx >> 4, c16 = idx & 15;
        const int row = m0 + r;
        uint4 v = make_uint4(0u, 0u, 0u, 0u);
        if (row < M) v = *(const uint4*)(agg16d + (size_t)row * 64 + c16 * 4);
        *(uint4*)(ATb + r * 256 + ((c16 * 16) ^ ((r & 7) << 4))) = v;
    }
    __syncthreads();

    const int lane = tid & 63;
    const int w    = tid >> 6;
    const int fr   = lane & 15;
    const int fg   = lane >> 4;
    const int ar0  = w * 32 + fr;
    const int asz  = (ar0 & 7) << 4;

    f32x4 acc[2][8];
#pragma unroll
    for (int a = 0; a < 2; ++a)
#pragma unroll
        for (int b = 0; b < 8; ++b) acc[a][b] = (f32x4){0.f, 0.f, 0.f, 0.f};

    // --- MFMA 1: B from global wf1 ---
#pragma unroll
    for (int ks = 0; ks < 4; ++ks) {
        const int kb = ks * 64 + fg * 16;
        const f16x8 a0 = *(const f16x8*)(ATb + ar0 * 256 + (kb ^ asz));
        const f16x8 a1 = *(const f16x8*)(ATb + (ar0 + 16) * 256 + (kb ^ asz));
        f16x8 bf[8];
#pragma unroll
        for (int cb = 0; cb < 8; ++cb)
            bf[cb] = *(const f16x8*)(wf1 + (cb * 16 + fr) * 128 + ks * 32 + fg * 8);
#pragma unroll
        for (int cb = 0; cb < 8; ++cb) {
            acc[0][cb] = __builtin_amdgcn_mfma_f32_16x16x32_f16(a0, bf[cb], acc[0][cb], 0, 0, 0);
            acc[1][cb] = __builtin_amdgcn_mfma_f32_16x16x32_f16(a1, bf[cb], acc[1][cb], 0, 0, 0);
        }
    }
    __syncthreads();

    // --- write relu(h1) tile into ATb (fp16, same swizzled layout) ---
    {
        float b1v[8];
#pragma unroll
        for (int cb = 0; cb < 8; ++cb) b1v[cb] = b1[cb * 16 + fr];
#pragma unroll
        for (int rf = 0; rf < 2; ++rf) {
            const int rb = w * 32 + rf * 16 + fg * 4;
#pragma unroll
            for (int cb = 0; cb < 8; ++cb) {
                const int cc = cb * 16 + fr;
#pragma unroll
                for (int j = 0; j < 4; ++j) {
                    const int r = rb + j;
                    const float v = fmaxf(acc[rf][cb][j] + b1v[cb], 0.f);
                    *(ushort_t*)(ATb + r * 256 + ((cc * 2) ^ ((r & 7) << 4))) = f2h(v);
                }
            }
        }
    }
#pragma unroll
    for (int a = 0; a < 2; ++a)
#pragma unroll
        for (int b = 0; b < 8; ++b) acc[a][b] = (f32x4){0.f, 0.f, 0.f, 0.f};
    __syncthreads();

    // --- MFMA 2: B from global wf2 ---
#pragma unroll
    for (int ks = 0; ks < 4; ++ks) {
        const int kb = ks * 64 + fg * 16;
        const f16x8 a0 = *(const f16x8*)(ATb + ar0 * 256 + (kb ^ asz));
        const f16x8 a1 = *(const f16x8*)(ATb + (ar0 + 16) * 256 + (kb ^ asz));
        f16x8 bf[8];
#pragma unroll
        for (int cb = 0; cb < 8; ++cb)
            bf[cb] = *(const f16x8*)(wf2 + (cb * 16 + fr) * 128 + ks * 32 + fg * 8);
#pragma unroll
        for (int cb = 0; cb < 8; ++cb) {
            acc[0][cb] = __builtin_amdgcn_mfma_f32_16x16x32_f16(a0, bf[cb], acc[0][cb], 0, 0, 0);
            acc[1][cb] = __builtin_amdgcn_mfma_f32_16x16x32_f16(a1, bf[cb], acc[1][cb], 0, 0, 0);
        }
    }

    // --- epilogue: bias, BN sums, fp16 h out ---
    float b2v[8];
#pragma unroll
    for (int cb = 0; cb < 8; ++cb) b2v[cb] = b2[cb * 16 + fr];
    float s[8], q[8];
#pragma unroll
    for (int cb = 0; cb < 8; ++cb) { s[cb] = 0.f; q[cb] = 0.f; }

#pragma unroll
    for (int rf = 0; rf < 2; ++rf) {
        const int r0 = m0 + w * 32 + rf * 16 + fg * 4;
#pragma unroll
        for (int cb = 0; cb < 8; ++cb) {
            const int col = cb * 16 + fr;
#pragma unroll
            for (int j = 0; j < 4; ++j) {
                const int row = r0 + j;
                if (row < M) {
                    const float v = acc[rf][cb][j] + b2v[cb];
                    h16[(size_t)row * 128 + col] = f2h(v);
                    s[cb] += v;
                    q[cb] += v * v;
                }
            }
        }
    }
#pragma unroll
    for (int cb = 0; cb < 8; ++cb) {
        float ss = s[cb]; ss += __shfl_down(ss, 32); ss += __shfl_down(ss, 16);
        float qq = q[cb]; qq += __shfl_down(qq, 32); qq += __shfl_down(qq, 16);
        if (lane < 16) {
            atomicAdd(&bsum[cb * 16 + lane], ss);
            atomicAdd(&bsum[128 + cb * 16 + lane], qq);
        }
    }
    __syncthreads();
    unsafeAtomicAdd(&sums[tid], bsum[tid]);
}

// ---------------------------------------------------------------------------
extern "C" void kernel_launch(void* const* d_in, const int* in_sizes, int n_in,
                              void* d_out, int out_size, void* d_ws, size_t ws_size,
                              hipStream_t stream)
{
    const float* x_in  = (const float*)d_in[0];
    const int*   ei    = (const int*)  d_in[1];
    const float* ea    = (const float*)d_in[2];
    const float* W_lin = (const float*)d_in[3];
    const float* b_lin = (const float*)d_in[4];
    const float* W1    = (const float*)d_in[5];
    const float* b1    = (const float*)d_in[6];
    const float* W2    = (const float*)d_in[7];
    const float* b2    = (const float*)d_in[8];
    const float* gamma = (const float*)d_in[9];
    const float* beta  = (const float*)d_in[10];

    const int N = in_sizes[0] / D_DIM;              // 50000
    const int E = in_sizes[2] / EDGE_DIM;           // 600000
    const int L = in_sizes[3] / (EDGE_DIM * D_DIM); // 3
    const int nchunks = (E + CHUNK - 1) / CHUNK;
    const float invN = 1.f / (float)N;

    const int* src = ei;
    const int* dst = ei + E;

    float* out = (float*)d_out;

    char* wp = (char*)d_ws;
    auto take = [&wp](size_t bytes) {
        char* r = wp;
        wp += (bytes + 15) & ~(size_t)15;
        return r;
    };
    unsigned*  agg16d  = (unsigned*) take((size_t)N * D_DIM * 2);
    ushort_t*  h16     = (ushort_t*) take((size_t)N * D_DIM * 2);
    unsigned*  x16d    = (unsigned*) take((size_t)N * D_DIM * 2);
    float*     sums3   = (float*)    take(3 * 256 * 4);
    unsigned*  wl3     = (unsigned*) take(3 * 2048 * 4);
    unsigned*  wf13    = (unsigned*) take(3 * 8192 * 4);
    unsigned*  wf23    = (unsigned*) take(3 * 8192 * 4);
    int*       cnt     = (int*)      take((size_t)N * 4);
    int*       row_off = (int*)      take((size_t)(N + 1) * 4);
    int*       cur     = (int*)      take((size_t)N * 4);
    int*       blksum  = (int*)      take(256 * 4);
    int*       chunk1  = (int*)      take((size_t)(nchunks + 1) * 4);
    int*       srcs    = (int*)      take((size_t)E * 4);
    uint4*     ea16q   = (uint4*)    take(((size_t)E + ECAP + 16) * 64);

    const int gemmBlocks = (N + 127) / 128;
    const int scanBlocks = (N + 2047) / 2048;

    // ---- preamble (once per call) ----
    hipMemsetAsync(cnt, 0, (size_t)N * sizeof(int), stream);
    hipMemsetAsync(sums3, 0, 3 * 256 * sizeof(float), stream);
    hipMemsetAsync(chunk1, 0x7f, (size_t)(nchunks + 1) * sizeof(int), stream);
    hist_kernel<<<1024, 256, 0, stream>>>(dst, cnt, E);
    scan_local_kernel<<<scanBlocks, 256, 0, stream>>>(cnt, row_off, blksum, N);
    scan_tops_kernel<<<1, 64, 0, stream>>>(blksum, row_off, N, scanBlocks);
    scan_add_kernel<<<scanBlocks, 256, 0, stream>>>(row_off, cur, blksum, N);
    chunk_first_kernel<<<(N + 255) / 256, 256, 0, stream>>>(row_off, chunk1, N, nchunks);
    scatter_conv_kernel<<<1024, 256, 0, stream>>>(src, dst, ea, cur, srcs, ea16q, E);
    wbuild_all_kernel<<<216, 256, 0, stream>>>(W_lin, W1, W2, wl3, wf13, wf23);
    xprep0_kernel<<<1024, 256, 0, stream>>>(x_in, (uint2*)x16d, N);

    // ---- layers: 2 launches each ----
    for (int l = 0; l < L; ++l) {
        const float* bl_l = b_lin + (size_t)l * D_DIM;
        const float* b1_l = b1 + (size_t)l * D_DIM;
        const float* b2_l = b2 + (size_t)l * D_DIM;
        const ushort_t* wl_l  = (const ushort_t*)(wl3 + (size_t)l * 2048);
        const ushort_t* wf1_l = (const ushort_t*)(wf13 + (size_t)l * 8192);
        const ushort_t* wf2_l = (const ushort_t*)(wf23 + (size_t)l * 8192);

        if (l == 0) {
            fused_edge_kernel<0><<<nchunks, 256, 0, stream>>>(
                x16d, srcs, (const ushort_t*)ea16q, wl_l, bl_l,
                row_off, chunk1, nullptr, nullptr, nullptr, invN, agg16d, N);
        } else {
            fused_edge_kernel<1><<<nchunks, 256, 0, stream>>>(
                (const unsigned*)h16, srcs, (const ushort_t*)ea16q, wl_l, bl_l,
                row_off, chunk1,
                sums3 + (size_t)(l - 1) * 256,
                gamma + (size_t)(l - 1) * D_DIM,
                beta + (size_t)(l - 1) * D_DIM, invN, agg16d, N);
        }

        fused_mlp_kernel<<<gemmBlocks, 256, 0, stream>>>(
            agg16d, wf1_l, b1_l, wf2_l, b2_l, h16,
            sums3 + (size_t)l * 256, N);
    }

    apply_final_kernel<<<1024, 256, 0, stream>>>(
        h16, sums3 + 2 * 256, gamma + 2 * D_DIM, beta + 2 * D_DIM,
        invN, out, N);
}

// Round 19
// 385.652 us; speedup vs baseline: 1.1952x; 1.0486x over previous
//
#include <hip/hip_runtime.h>

#define D_DIM 128
#define EDGE_DIM 32
#define BN_EPS 1e-5f
#define CHUNK 48
#define ECAP 96

typedef __attribute__((ext_vector_type(8))) _Float16 f16x8;
typedef __attribute__((ext_vector_type(2))) _Float16 half2v;
typedef __attribute__((ext_vector_type(4))) float f32x4;
typedef unsigned short ushort_t;

__device__ __forceinline__ unsigned short f2h(float f) {
    union { _Float16 h; unsigned short u; } c;
    c.h = (_Float16)f;
    return c.u;
}
__device__ __forceinline__ unsigned pk2h(float lo, float hi) {
    return (unsigned)f2h(lo) | ((unsigned)f2h(hi) << 16);
}
__device__ __forceinline__ half2v asH2(unsigned u) {
    union { unsigned u; half2v h; } c;
    c.u = u;
    return c.h;
}

// ---------------------------------------------------------------------------
// CSR build: histogram -> multi-block scan -> scatter(+fp16 convert)
// ---------------------------------------------------------------------------
__global__ __launch_bounds__(256) void hist_kernel(
    const int* __restrict__ dst, int* __restrict__ cnt, int E)
{
    for (int e = blockIdx.x * 256 + threadIdx.x; e < E; e += gridDim.x * 256)
        atomicAdd(&cnt[dst[e]], 1);
}

__global__ __launch_bounds__(256) void scan_local_kernel(
    const int* __restrict__ cnt, int* __restrict__ off,
    int* __restrict__ blksum, int n)
{
    __shared__ int part[256];
    const int t = threadIdx.x;
    const int base = blockIdx.x * 2048 + t * 8;
    int v[8];
    int s = 0;
#pragma unroll
    for (int j = 0; j < 8; ++j) {
        const int idx = base + j;
        const int c = (idx < n) ? cnt[idx] : 0;
        v[j] = s;
        s += c;
    }
    part[t] = s;
    __syncthreads();
    for (int d = 1; d < 256; d <<= 1) {
        const int val = (t >= d) ? part[t - d] : 0;
        __syncthreads();
        part[t] += val;
        __syncthreads();
    }
    const int texcl = (t > 0) ? part[t - 1] : 0;
#pragma unroll
    for (int j = 0; j < 8; ++j) {
        const int idx = base + j;
        if (idx < n) off[idx] = texcl + v[j];
    }
    if (t == 255) blksum[blockIdx.x] = part[255];
}

__global__ __launch_bounds__(64) void scan_tops_kernel(
    int* __restrict__ blksum, int* __restrict__ off, int n, int B)
{
    if (threadIdx.x == 0) {
        int run = 0;
        for (int b = 0; b < B; ++b) {
            const int v = blksum[b];
            blksum[b] = run;
            run += v;
        }
        off[n] = run;
    }
}

__global__ __launch_bounds__(256) void scan_add_kernel(
    int* __restrict__ off, int* __restrict__ cur,
    const int* __restrict__ blksum, int n)
{
    const int base = blockIdx.x * 2048;
    const int add = blksum[blockIdx.x];
    for (int j = threadIdx.x; j < 2048; j += 256) {
        const int i = base + j;
        if (i < n) {
            const int v = off[i] + add;
            off[i] = v;
            cur[i] = v;
        }
    }
}

// scatter + inline edge_attr fp16 conversion into CSR order
__global__ __launch_bounds__(256) void scatter_conv_kernel(
    const int* __restrict__ src, const int* __restrict__ dst,
    const float* __restrict__ ea,
    int* __restrict__ cur, int* __restrict__ srcs,
    uint4* __restrict__ ea16q, int E)
{
    for (int e = blockIdx.x * 256 + threadIdx.x; e < E; e += gridDim.x * 256) {
        const int p = atomicAdd(&cur[dst[e]], 1);
        srcs[p] = src[e];
        const float* __restrict__ er = ea + (size_t)e * EDGE_DIM;
#pragma unroll
        for (int q = 0; q < 4; ++q) {
            const float4 a = *(const float4*)(er + q * 8);
            const float4 b = *(const float4*)(er + q * 8 + 4);
            uint4 o;
            o.x = pk2h(a.x, a.y); o.y = pk2h(a.z, a.w);
            o.z = pk2h(b.x, b.y); o.w = pk2h(b.z, b.w);
            ea16q[(size_t)p * 4 + q] = o;
        }
    }
}

// ---------------------------------------------------------------------------
// chunk_first[c] = first node whose CSR row starts in edge-window c (CHUNK).
// chunk_first pre-filled with 0x7f7f7f7f; [nchunks] set to n here.
// ---------------------------------------------------------------------------
__global__ __launch_bounds__(256) void chunk_first_kernel(
    const int* __restrict__ row_off, int* __restrict__ chunk_first,
    int n, int nchunks)
{
    const int i = blockIdx.x * 256 + threadIdx.x;
    if (i == 0) chunk_first[nchunks] = n;
    if (i < n) {
        int c = row_off[i] / CHUNK;
        if (c > nchunks - 1) c = nchunks - 1;
        atomicMin(&chunk_first[c], i);
    }
}

// ---------------------------------------------------------------------------
// ALL-layer weight prep (one launch):
//   wl3 : W_lin MFMA B-fragment layout, per layer 2048 dwords.
//   wf13/wf23 : W1/W2 fragment-linear fp16, per layer 8192 dwords
// ---------------------------------------------------------------------------
__global__ __launch_bounds__(256) void wbuild_all_kernel(
    const float* __restrict__ W_lin, const float* __restrict__ W1,
    const float* __restrict__ W2,
    unsigned* __restrict__ wl3, unsigned* __restrict__ wf13,
    unsigned* __restrict__ wf23)
{
    const int idx = blockIdx.x * 256 + threadIdx.x;
    if (idx >= 3 * 18432) return;
    const int l = idx / 18432;
    const int r = idx % 18432;
    const float* Wl  = W_lin + (size_t)l * EDGE_DIM * D_DIM;
    const float* W1l = W1 + (size_t)l * D_DIM * D_DIM;
    const float* W2l = W2 + (size_t)l * D_DIM * D_DIM;
    if (r < 2048) {
        const int slot = r >> 2, q = r & 3;
        const int cb = slot >> 6, lane = slot & 63;
        const int col = cb * 16 + (lane & 15);
        const int k0 = (lane >> 4) * 8 + 2 * q;
        wl3[l * 2048 + r] = pk2h(Wl[k0 * D_DIM + col], Wl[(k0 + 1) * D_DIM + col]);
    } else if (r < 10240) {
        const int i = r - 2048;
        const int col = i >> 6, kp = i & 63;
        wf13[l * 8192 + i] = pk2h(W1l[(2 * kp) * D_DIM + col], W1l[(2 * kp + 1) * D_DIM + col]);
    } else {
        const int i = r - 10240;
        const int col = i >> 6, kp = i & 63;
        wf23[l * 8192 + i] = pk2h(W2l[(2 * kp) * D_DIM + col], W2l[(2 * kp + 1) * D_DIM + col]);
    }
}

// ---------------------------------------------------------------------------
// xprep0: fp32 x -> fp16 x16 (layer 0 only)
// ---------------------------------------------------------------------------
__global__ __launch_bounds__(256) void xprep0_kernel(
    const float* __restrict__ h, uint2* __restrict__ x16q, int M)
{
    const int total = M * 32;
    for (int i = blockIdx.x * 256 + threadIdx.x; i < total; i += gridDim.x * 256) {
        const float4 v = ((const float4*)h)[i];
        uint2 o; o.x = pk2h(v.x, v.y); o.y = pk2h(v.z, v.w);
        x16q[i] = o;
    }
}

// ---------------------------------------------------------------------------
// final apply: out = relu(h16*sc + sh), sc/sh computed in-block from sums.
// ---------------------------------------------------------------------------
__global__ __launch_bounds__(256) void apply_final_kernel(
    const ushort_t* __restrict__ h16, const float* __restrict__ sums,
    const float* __restrict__ gamma, const float* __restrict__ beta,
    float invN, float* __restrict__ outp, int M)
{
    __shared__ float sc[128], sh[128];
    if (threadIdx.x < 128) {
        const int c = threadIdx.x;
        const float mu  = sums[c] * invN;
        const float var = sums[128 + c] * invN - mu * mu;
        const float s   = gamma[c] * rsqrtf(var + BN_EPS);
        sc[c] = s;
        sh[c] = beta[c] - mu * s;
    }
    __syncthreads();
    const int total = M * 32;
    for (int i = blockIdx.x * 256 + threadIdx.x; i < total; i += gridDim.x * 256) {
        const uint2 hv = *(const uint2*)(h16 + (size_t)i * 4);
        const half2v a = asH2(hv.x), b = asH2(hv.y);
        const int c = (i & 31) * 4;
        f32x4 o;
        o[0] = fmaxf(fmaf((float)a.x, sc[c + 0], sh[c + 0]), 0.f);
        o[1] = fmaxf(fmaf((float)a.y, sc[c + 1], sh[c + 1]), 0.f);
        o[2] = fmaxf(fmaf((float)b.x, sc[c + 2], sh[c + 2]), 0.f);
        o[3] = fmaxf(fmaf((float)b.y, sc[c + 3], sh[c + 3]), 0.f);
        *(f32x4*)(outp + (size_t)i * 4) = o;
    }
}

// ---------------------------------------------------------------------------
// Fused edge pass, node-aligned 48-edge chunks (6 blocks/CU):
//   phase 1: e = ea@W_lin + b_lin via MFMA -> eT[edge][col] fp16 in LDS
//   phase 2: waves split the chunk's nodes; per node batch-4 gather
//            x16[src] (+inline prev BN) + e; plain-store
//            agg16[n] = fp16(x_n + sum relu(...)).  No atomics.
// ---------------------------------------------------------------------------
template<int XFORM>
__global__ __launch_bounds__(256, 6) void fused_edge_kernel(
    const unsigned* __restrict__ hsrc,     // N x 64 dwords: x16 (l=0) or h16
    const int*      __restrict__ srcs,
    const ushort_t* __restrict__ ea16,     // CSR order, padded
    const ushort_t* __restrict__ wflin,    // B-fragment layout, 4096 halfs
    const float*    __restrict__ bl,
    const int*      __restrict__ row_off,
    const int*      __restrict__ chunk_first,
    const float*    __restrict__ sums,     // prev layer BN sums (XFORM)
    const float*    __restrict__ gamma,
    const float*    __restrict__ beta,
    float invN,
    unsigned*       __restrict__ agg16d,
    int nNodes)
{
    __shared__ ushort_t eT[ECAP * 132];
    const int tid  = threadIdx.x;
    const int lane = tid & 63;
    const int w    = tid >> 6;
    const int fr   = lane & 15;
    const int fg   = lane >> 4;
    const int c    = blockIdx.x;

    int nfirst = chunk_first[c];
    int nlast  = chunk_first[c + 1];
    if (nfirst > nNodes) nfirst = nNodes;
    if (nlast  > nNodes) nlast  = nNodes;
    if (nfirst >= nlast) return;      // block-uniform; barrier never reached
    const int ebase = row_off[nfirst];
    const int ecnt  = row_off[nlast] - ebase;

    // ---- phase 1: MFMA e-tile ----
    f16x8 bfr[8];
#pragma unroll
    for (int cb = 0; cb < 8; ++cb)
        bfr[cb] = *(const f16x8*)(wflin + (cb * 64 + lane) * 8);
    float blv[8];
#pragma unroll
    for (int cb = 0; cb < 8; ++cb) blv[cb] = bl[cb * 16 + fr];

    const int rowblocks = (ecnt + 15) >> 4;   // <= ceil(ECAP/16) = 6
#pragma unroll
    for (int rr = 0; rr < 2; ++rr) {
        const int rb = w + rr * 4;
        if (rb < rowblocks) {
            const f16x8 af = *(const f16x8*)(ea16
                + ((size_t)(ebase + rb * 16 + fr)) * 32 + fg * 8);
            f32x4 acc[8];
#pragma unroll
            for (int cb = 0; cb < 8; ++cb) {
                const f32x4 z = {0.f, 0.f, 0.f, 0.f};
                acc[cb] = __builtin_amdgcn_mfma_f32_16x16x32_f16(af, bfr[cb], z, 0, 0, 0);
            }
#pragma unroll
            for (int cb = 0; cb < 8; ++cb) {
                const int col = cb * 16 + fr;
#pragma unroll
                for (int j = 0; j < 4; ++j) {
                    const int er = rb * 16 + fg * 4 + j;
                    eT[er * 132 + col] = f2h(acc[cb][j] + blv[cb]);
                }
            }
        }
    }
    __syncthreads();

    // ---- phase 2: node-parallel, batch-4 ILP, plain stores ----
    float scl0 = 1.f, shl0 = 0.f, scl1 = 1.f, shl1 = 0.f;
    if (XFORM) {
        const int c0 = 2 * lane, c1 = 2 * lane + 1;
        const float mu0 = sums[c0] * invN;
        const float va0 = sums[128 + c0] * invN - mu0 * mu0;
        scl0 = gamma[c0] * rsqrtf(va0 + BN_EPS);
        shl0 = beta[c0] - mu0 * scl0;
        const float mu1 = sums[c1] * invN;
        const float va1 = sums[128 + c1] * invN - mu1 * mu1;
        scl1 = gamma[c1] * rsqrtf(va1 + BN_EPS);
        shl1 = beta[c1] - mu1 * scl1;
    }

    for (int n = nfirst + w; n < nlast; n += 4) {
        const int beg = __builtin_amdgcn_readfirstlane(row_off[n]);
        const int end = __builtin_amdgcn_readfirstlane(row_off[n + 1]);
        float a0 = 0.f, a1 = 0.f;
        int p = beg;
        const int head = (end - beg) & 3;
#pragma unroll 1
        for (int t = 0; t < head; ++t, ++p) {
            const int s = __builtin_amdgcn_readfirstlane(srcs[p]);
            const unsigned xd = hsrc[(size_t)s * 64 + lane];
            const unsigned ed = *(const unsigned*)&eT[(p - ebase) * 132 + 2 * lane];
            const half2v xh = asH2(xd), eh = asH2(ed);
            float x0 = (float)xh.x, x1 = (float)xh.y;
            if (XFORM) {
                x0 = fmaxf(fmaf(x0, scl0, shl0), 0.f);
                x1 = fmaxf(fmaf(x1, scl1, shl1), 0.f);
            }
            a0 += fmaxf(x0 + (float)eh.x, 0.f);
            a1 += fmaxf(x1 + (float)eh.y, 0.f);
        }
#pragma unroll 1
        for (; p < end; p += 4) {
            const int s0 = __builtin_amdgcn_readfirstlane(srcs[p]);
            const int s1 = __builtin_amdgcn_readfirstlane(srcs[p + 1]);
            const int s2 = __builtin_amdgcn_readfirstlane(srcs[p + 2]);
            const int s3 = __builtin_amdgcn_readfirstlane(srcs[p + 3]);
            const unsigned x0d = hsrc[(size_t)s0 * 64 + lane];
            const unsigned x1d = hsrc[(size_t)s1 * 64 + lane];
            const unsigned x2d = hsrc[(size_t)s2 * 64 + lane];
            const unsigned x3d = hsrc[(size_t)s3 * 64 + lane];
            const int ei = p - ebase;
            const unsigned e0 = *(const unsigned*)&eT[(ei + 0) * 132 + 2 * lane];
            const unsigned e1 = *(const unsigned*)&eT[(ei + 1) * 132 + 2 * lane];
            const unsigned e2 = *(const unsigned*)&eT[(ei + 2) * 132 + 2 * lane];
            const unsigned e3 = *(const unsigned*)&eT[(ei + 3) * 132 + 2 * lane];
#pragma unroll
            for (int t = 0; t < 4; ++t) {
                const unsigned xd = (t == 0) ? x0d : (t == 1) ? x1d : (t == 2) ? x2d : x3d;
                const unsigned ed = (t == 0) ? e0 : (t == 1) ? e1 : (t == 2) ? e2 : e3;
                const half2v xh = asH2(xd), eh = asH2(ed);
                float x0 = (float)xh.x, x1 = (float)xh.y;
                if (XFORM) {
                    x0 = fmaxf(fmaf(x0, scl0, shl0), 0.f);
                    x1 = fmaxf(fmaf(x1, scl1, shl1), 0.f);
                }
                a0 += fmaxf(x0 + (float)eh.x, 0.f);
                a1 += fmaxf(x1 + (float)eh.y, 0.f);
            }
        }
        // GIN self-term folded: agg16 = fp16(x_n + sum)
        const half2v xo = asH2(hsrc[(size_t)n * 64 + lane]);
        float x0 = (float)xo.x, x1 = (float)xo.y;
        if (XFORM) {
            x0 = fmaxf(fmaf(x0, scl0, shl0), 0.f);
            x1 = fmaxf(fmaf(x1, scl1, shl1), 0.f);
        }
        agg16d[(size_t)n * 64 + lane] = pk2h(x0 + a0, x1 + a1);
    }
}

// ---------------------------------------------------------------------------
// Fused MLP: h16 = (relu(agg16@W1+b1)) @ W2 + b2 (+BN sums).
// A staged once in LDS (32 KB, swizzled, pure fp16 copy). B-fragments read
// directly from global fragment-linear wfrag (L2-hot). ks=0 W1 fragments
// hoisted above the barrier to overlap A-stage latency.
// ---------------------------------------------------------------------------
__global__ __launch_bounds__(256) void fused_mlp_kernel(
    const unsigned* __restrict__ agg16d,
    const ushort_t* __restrict__ wf1,
    const float* __restrict__ b1,
    const ushort_t* __restrict__ wf2,
    const float* __restrict__ b2,
    ushort_t* __restrict__ h16,
    float* __restrict__ sums,
    int M)
{
    __shared__ char ATb[128 * 256];
    __shared__ float bsum[256];
    const int tid = threadIdx.x;
    const int m0  = blockIdx.x * 128;

    bsum[tid] = 0.f;

    const int lane = tid & 63;
    const int w    = tid >> 6;
    const int fr   = lane & 15;
    const int fg   = lane >> 4;

    // hoisted W1 ks=0 fragments (overlap with A-stage + barrier)
    f16x8 bf0[8];
#pragma unroll
    for (int cb = 0; cb < 8; ++cb)
        bf0[cb] = *(const f16x8*)(wf1 + (cb * 16 + fr) * 128 + fg * 8);

    // --- stage A: pure fp16 copy, XOR-swizzled ---
#pragma unroll
    for (int i = 0; i < 8; ++i) {
        const int idx = i * 256 + tid;
        const int r = idx >> 4, c16 = idx & 15;
        const int row = m0 + r;
        uint4 v = make_uint4(0u, 0u, 0u, 0u);
        if (row < M) v = *(const uint4*)(agg16d + (size_t)row * 64 + c16 * 4);
        *(uint4*)(ATb + r * 256 + ((c16 * 16) ^ ((r & 7) << 4))) = v;
    }
    __syncthreads();

    const int ar0  = w * 32 + fr;
    const int asz  = (ar0 & 7) << 4;

    f32x4 acc[2][8];
#pragma unroll
    for (int a = 0; a < 2; ++a)
#pragma unroll
        for (int b = 0; b < 8; ++b) acc[a][b] = (f32x4){0.f, 0.f, 0.f, 0.f};

    // --- MFMA 1: B from global wf1 (ks=0 from hoisted regs) ---
#pragma unroll
    for (int ks = 0; ks < 4; ++ks) {
        const int kb = ks * 64 + fg * 16;
        const f16x8 a0 = *(const f16x8*)(ATb + ar0 * 256 + (kb ^ asz));
        const f16x8 a1 = *(const f16x8*)(ATb + (ar0 + 16) * 256 + (kb ^ asz));
        f16x8 bf[8];
        if (ks == 0) {
#pragma unroll
            for (int cb = 0; cb < 8; ++cb) bf[cb] = bf0[cb];
        } else {
#pragma unroll
            for (int cb = 0; cb < 8; ++cb)
                bf[cb] = *(const f16x8*)(wf1 + (cb * 16 + fr) * 128 + ks * 32 + fg * 8);
        }
#pragma unroll
        for (int cb = 0; cb < 8; ++cb) {
            acc[0][cb] = __builtin_amdgcn_mfma_f32_16x16x32_f16(a0, bf[cb], acc[0][cb], 0, 0, 0);
            acc[1][cb] = __builtin_amdgcn_mfma_f32_16x16x32_f16(a1, bf[cb], acc[1][cb], 0, 0, 0);
        }
    }
    __syncthreads();

    // --- write relu(h1) tile into ATb (fp16, same swizzled layout) ---
    {
        float b1v[8];
#pragma unroll
        for (int cb = 0; cb < 8; ++cb) b1v[cb] = b1[cb * 16 + fr];
#pragma unroll
        for (int rf = 0; rf < 2; ++rf) {
            const int rb = w * 32 + rf * 16 + fg * 4;
#pragma unroll
            for (int cb = 0; cb < 8; ++cb) {
                const int cc = cb * 16 + fr;
#pragma unroll
                for (int j = 0; j < 4; ++j) {
                    const int r = rb + j;
                    const float v = fmaxf(acc[rf][cb][j] + b1v[cb], 0.f);
                    *(ushort_t*)(ATb + r * 256 + ((cc * 2) ^ ((r & 7) << 4))) = f2h(v);
                }
            }
        }
    }
#pragma unroll
    for (int a = 0; a < 2; ++a)
#pragma unroll
        for (int b = 0; b < 8; ++b) acc[a][b] = (f32x4){0.f, 0.f, 0.f, 0.f};
    __syncthreads();

    // --- MFMA 2: B from global wf2 ---
#pragma unroll
    for (int ks = 0; ks < 4; ++ks) {
        const int kb = ks * 64 + fg * 16;
        const f16x8 a0 = *(const f16x8*)(ATb + ar0 * 256 + (kb ^ asz));
        const f16x8 a1 = *(const f16x8*)(ATb + (ar0 + 16) * 256 + (kb ^ asz));
        f16x8 bf[8];
#pragma unroll
        for (int cb = 0; cb < 8; ++cb)
            bf[cb] = *(const f16x8*)(wf2 + (cb * 16 + fr) * 128 + ks * 32 + fg * 8);
#pragma unroll
        for (int cb = 0; cb < 8; ++cb) {
            acc[0][cb] = __builtin_amdgcn_mfma_f32_16x16x32_f16(a0, bf[cb], acc[0][cb], 0, 0, 0);
            acc[1][cb] = __builtin_amdgcn_mfma_f32_16x16x32_f16(a1, bf[cb], acc[1][cb], 0, 0, 0);
        }
    }

    // --- epilogue: bias, BN sums, fp16 h out ---
    float b2v[8];
#pragma unroll
    for (int cb = 0; cb < 8; ++cb) b2v[cb] = b2[cb * 16 + fr];
    float s[8], q[8];
#pragma unroll
    for (int cb = 0; cb < 8; ++cb) { s[cb] = 0.f; q[cb] = 0.f; }

#pragma unroll
    for (int rf = 0; rf < 2; ++rf) {
        const int r0 = m0 + w * 32 + rf * 16 + fg * 4;
#pragma unroll
        for (int cb = 0; cb < 8; ++cb) {
            const int col = cb * 16 + fr;
#pragma unroll
            for (int j = 0; j < 4; ++j) {
                const int row = r0 + j;
                if (row < M) {
                    const float v = acc[rf][cb][j] + b2v[cb];
                    h16[(size_t)row * 128 + col] = f2h(v);
                    s[cb] += v;
                    q[cb] += v * v;
                }
            }
        }
    }
#pragma unroll
    for (int cb = 0; cb < 8; ++cb) {
        float ss = s[cb]; ss += __shfl_down(ss, 32); ss += __shfl_down(ss, 16);
        float qq = q[cb]; qq += __shfl_down(qq, 32); qq += __shfl_down(qq, 16);
        if (lane < 16) {
            atomicAdd(&bsum[cb * 16 + lane], ss);
            atomicAdd(&bsum[128 + cb * 16 + lane], qq);
        }
    }
    __syncthreads();
    unsafeAtomicAdd(&sums[tid], bsum[tid]);
}

// ---------------------------------------------------------------------------
extern "C" void kernel_launch(void* const* d_in, const int* in_sizes, int n_in,
                              void* d_out, int out_size, void* d_ws, size_t ws_size,
                              hipStream_t stream)
{
    const float* x_in  = (const float*)d_in[0];
    const int*   ei    = (const int*)  d_in[1];
    const float* ea    = (const float*)d_in[2];
    const float* W_lin = (const float*)d_in[3];
    const float* b_lin = (const float*)d_in[4];
    const float* W1    = (const float*)d_in[5];
    const float* b1    = (const float*)d_in[6];
    const float* W2    = (const float*)d_in[7];
    const float* b2    = (const float*)d_in[8];
    const float* gamma = (const float*)d_in[9];
    const float* beta  = (const float*)d_in[10];

    const int N = in_sizes[0] / D_DIM;              // 50000
    const int E = in_sizes[2] / EDGE_DIM;           // 600000
    const int L = in_sizes[3] / (EDGE_DIM * D_DIM); // 3
    const int nchunks = (E + CHUNK - 1) / CHUNK;
    const float invN = 1.f / (float)N;

    const int* src = ei;
    const int* dst = ei + E;

    float* out = (float*)d_out;

    char* wp = (char*)d_ws;
    auto take = [&wp](size_t bytes) {
        char* r = wp;
        wp += (bytes + 15) & ~(size_t)15;
        return r;
    };
    unsigned*  agg16d  = (unsigned*) take((size_t)N * D_DIM * 2);
    ushort_t*  h16     = (ushort_t*) take((size_t)N * D_DIM * 2);
    unsigned*  x16d    = (unsigned*) take((size_t)N * D_DIM * 2);
    float*     sums3   = (float*)    take(3 * 256 * 4);
    unsigned*  wl3     = (unsigned*) take(3 * 2048 * 4);
    unsigned*  wf13    = (unsigned*) take(3 * 8192 * 4);
    unsigned*  wf23    = (unsigned*) take(3 * 8192 * 4);
    int*       cnt     = (int*)      take((size_t)N * 4);
    int*       row_off = (int*)      take((size_t)(N + 1) * 4);
    int*       cur     = (int*)      take((size_t)N * 4);
    int*       blksum  = (int*)      take(256 * 4);
    int*       chunk1  = (int*)      take((size_t)(nchunks + 1) * 4);
    int*       srcs    = (int*)      take((size_t)E * 4);
    uint4*     ea16q   = (uint4*)    take(((size_t)E + ECAP + 16) * 64);

    const int gemmBlocks = (N + 127) / 128;
    const int scanBlocks = (N + 2047) / 2048;

    // ---- preamble (once per call) ----
    hipMemsetAsync(cnt, 0, (size_t)N * sizeof(int), stream);
    hipMemsetAsync(sums3, 0, 3 * 256 * sizeof(float), stream);
    hipMemsetAsync(chunk1, 0x7f, (size_t)(nchunks + 1) * sizeof(int), stream);
    hist_kernel<<<1024, 256, 0, stream>>>(dst, cnt, E);
    scan_local_kernel<<<scanBlocks, 256, 0, stream>>>(cnt, row_off, blksum, N);
    scan_tops_kernel<<<1, 64, 0, stream>>>(blksum, row_off, N, scanBlocks);
    scan_add_kernel<<<scanBlocks, 256, 0, stream>>>(row_off, cur, blksum, N);
    chunk_first_kernel<<<(N + 255) / 256, 256, 0, stream>>>(row_off, chunk1, N, nchunks);
    scatter_conv_kernel<<<1024, 256, 0, stream>>>(src, dst, ea, cur, srcs, ea16q, E);
    wbuild_all_kernel<<<216, 256, 0, stream>>>(W_lin, W1, W2, wl3, wf13, wf23);
    xprep0_kernel<<<1024, 256, 0, stream>>>(x_in, (uint2*)x16d, N);

    // ---- layers: 2 launches each ----
    for (int l = 0; l < L; ++l) {
        const float* bl_l = b_lin + (size_t)l * D_DIM;
        const float* b1_l = b1 + (size_t)l * D_DIM;
        const float* b2_l = b2 + (size_t)l * D_DIM;
        const ushort_t* wl_l  = (const ushort_t*)(wl3 + (size_t)l * 2048);
        const ushort_t* wf1_l = (const ushort_t*)(wf13 + (size_t)l * 8192);
        const ushort_t* wf2_l = (const ushort_t*)(wf23 + (size_t)l * 8192);

        if (l == 0) {
            fused_edge_kernel<0><<<nchunks, 256, 0, stream>>>(
                x16d, srcs, (const ushort_t*)ea16q, wl_l, bl_l,
                row_off, chunk1, nullptr, nullptr, nullptr, invN, agg16d, N);
        } else {
            fused_edge_kernel<1><<<nchunks, 256, 0, stream>>>(
                (const unsigned*)h16, srcs, (const ushort_t*)ea16q, wl_l, bl_l,
                row_off, chunk1,
                sums3 + (size_t)(l - 1) * 256,
                gamma + (size_t)(l - 1) * D_DIM,
                beta + (size_t)(l - 1) * D_DIM, invN, agg16d, N);
        }

        fused_mlp_kernel<<<gemmBlocks, 256, 0, stream>>>(
            agg16d, wf1_l, b1_l, wf2_l, b2_l, h16,
            sums3 + (size_t)l * 256, N);
    }

    apply_final_kernel<<<1024, 256, 0, stream>>>(
        h16, sums3 + 2 * 256, gamma + 2 * D_DIM, beta + 2 * D_DIM,
        invN, out, N);
}